// Round 7
// baseline (2866.270 us; speedup 1.0000x reference)
//
#include <hip/hip_runtime.h>

#define NN 100000
#define NE 1600000
#define NG 64
#define MAXDEG 64

typedef long long i64;
typedef unsigned short u16;
typedef __attribute__((ext_vector_type(8))) _Float16 f16x8;
typedef __attribute__((ext_vector_type(4))) _Float16 half4;
typedef __attribute__((ext_vector_type(4))) float f32x4;

__device__ __forceinline__ float sigm(float x){ return 1.f/(1.f+__expf(-x)); }
__device__ __forceinline__ float tanh_(float x){ return 2.f/(1.f+__expf(-2.f*x)) - 1.f; }
__device__ __forceinline__ f32x4 mfma16h(f16x8 a, f16x8 b, f32x4 c){
  return __builtin_amdgcn_mfma_f32_16x16x32_f16(a,b,c,0,0,0);
}

// ---------------- int-width detection ----------------
__global__ __launch_bounds__(512) void k_detect(const int* __restrict__ ei,
    const int* __restrict__ batch, int* __restrict__ flags){
  int t = threadIdx.x;
  __shared__ int nz_e, nz_b;
  if (t == 0){ nz_e = 0; nz_b = 0; }
  __syncthreads();
  if (ei[2*t + 1] != 0) nz_e = 1;
  int k = NN/2 - 512 + t;
  if (batch[2*k + 1] != 0) nz_b = 1;
  __syncthreads();
  if (t == 0){ flags[0] = nz_e ? 0 : 1; flags[1] = nz_b ? 0 : 1; }
}

// ---------------- transposed GRU weights: wT[l][k][jc] = w[l][jc][k] ----------------
__global__ __launch_bounds__(256) void k_prep_wT(const float* __restrict__ wih,
    const float* __restrict__ whh, float* __restrict__ wihT, float* __restrict__ whhT){
  int idx = blockIdx.x*256 + threadIdx.x;            // 3*49152 = 147456
  if (idx >= 3*49152) return;
  int l = idx/49152, r = idx - l*49152, k = r/384, jc = r - k*384;
  wihT[idx] = wih[((size_t)l*384 + jc)*128 + k];
  whhT[idx] = whh[((size_t)l*384 + jc)*128 + k];
}

// ---------------- Weff fold: WeffT[li][k][jc] = sum_m cw[li][k][m] * wih[l][jc][m] ----------------
__global__ __launch_bounds__(384) void k_weff(const float* __restrict__ convw,
    const float* __restrict__ wihT, float* __restrict__ WeffT){
  int bid = blockIdx.x;               // 9*128
  int li = bid >> 7, k = bid & 127;
  int l = li / 3;
  int j = threadIdx.x;                // 0..383
  __shared__ float cwrow[128];
  if (j < 128) cwrow[j] = convw[((size_t)li*128 + k)*128 + j];
  __syncthreads();
  const float* wT = wihT + (size_t)l*49152;
  float acc = 0.f;
#pragma unroll 8
  for (int m = 0; m < 128; ++m)
    acc = fmaf(cwrow[m], wT[(size_t)m*384 + j], acc);
  WeffT[(size_t)li*49152 + (size_t)k*384 + j] = acc;
}

// ---------------- split fp16 B planes, MFMA-fragment-contiguous layout ----------------
// logical B[li][col(512)][k(256)]:
//   col<256: k<128 -> WeffT[li][k][col], k>=128 -> whhT[l][k-128][col]   (r,z)
//   col in [256,384): k<128 -> WeffT[li][k][col] else 0                   (inn)
//   col in [384,512): k>=128 -> whhT[l][k-128][col-128] else 0            (hn)
// storage idx (per li): (((k>>5)*512 + col)*4 + ((k>>3)&3))*8 + (k&7)
__global__ __launch_bounds__(256) void k_bsplit(const float* __restrict__ WeffT,
    const float* __restrict__ whhT, u16* __restrict__ Bhi, u16* __restrict__ Blo){
  int idx = blockIdx.x*256 + threadIdx.x;   // 9*512*256 exact
  int li = idx >> 17;
  int r = idx & 131071;
  int col = r >> 8, k = r & 255;
  int l = li / 3;
  float v = 0.f;
  if (k < 128){
    if (col < 384) v = WeffT[(size_t)li*49152 + (size_t)k*384 + col];
  } else {
    int k2 = k - 128;
    if (col < 256)       v = whhT[(size_t)l*49152 + (size_t)k2*384 + col];
    else if (col >= 384) v = whhT[(size_t)l*49152 + (size_t)k2*384 + (col-128)];
  }
  _Float16 hi = (_Float16)v;
  _Float16 lo = (_Float16)(v - (float)hi);
  size_t widx = (size_t)li*131072 + ((((size_t)(k>>5))*512 + col)*4 + ((k>>3)&3))*8 + (k&7);
  Bhi[widx] = *(const u16*)&hi;
  Blo[widx] = *(const u16*)&lo;
}

// ---------------- padded adjacency by dst ----------------
__global__ __launch_bounds__(256) void k_fill_edges(const int* __restrict__ ei,
    const int* __restrict__ flags, int* __restrict__ deg, int* __restrict__ col){
  int e = blockIdx.x*256 + threadIdx.x;
  if (e >= NE) return;
  int s, d;
  if (flags[0]){
    const i64* e64 = (const i64*)ei;
    s = (int)e64[e]; d = (int)e64[NE + e];
  } else {
    s = ei[e]; d = ei[NE + e];
  }
  int slot = atomicAdd(&deg[d], 1);
  if (slot < MAXDEG) col[(size_t)d*MAXDEG + slot] = s;
}

// ---------------- encoder: fp32, 8 nodes/block (unchanged, proven) ----------------
__global__ __launch_bounds__(128) void k_enc_n(const float* __restrict__ x,
    const float* __restrict__ pos, const float* __restrict__ w1, const float* __restrict__ b1,
    const float* __restrict__ w2, const float* __restrict__ b2, float* __restrict__ h){
  int n0 = blockIdx.x * 8, j = threadIdx.x;
  __shared__ float xr[8][68];
  __shared__ float t1[8][128];
  for (int q = j; q < 8*67; q += 128){
    int p = q/67, kk = q - p*67;
    xr[p][kk] = (kk < 64) ? x[(size_t)(n0+p)*64 + kk] : pos[(size_t)(n0+p)*3 + (kk-64)];
  }
  __syncthreads();
  float s[8];
#pragma unroll
  for (int p=0;p<8;++p) s[p] = b1[j];
  for (int k=0;k<67;++k){
    float w = w1[k*128 + j];
#pragma unroll
    for (int p=0;p<8;++p) s[p] = fmaf(xr[p][k], w, s[p]);
  }
#pragma unroll
  for (int p=0;p<8;++p) t1[p][j] = fmaxf(s[p], 0.f);
  __syncthreads();
#pragma unroll
  for (int p=0;p<8;++p) s[p] = b2[j];
  for (int k=0;k<128;++k){
    float w = w2[k*128 + j];
#pragma unroll
    for (int p=0;p<8;++p) s[p] = fmaf(t1[p][k], w, s[p]);
  }
#pragma unroll
  for (int p=0;p<8;++p) h[(size_t)(n0+p)*128 + j] = s[p];
}

// ---------------- FUSED: gather(SpMM) + split-fp16 3-pass MFMA GRU ----------------
// Reads hin (node states), writes hout (ping-pong; no intra-dispatch h hazard).
// LDS A = [ah | h] (K=256) hi/lo fp16, XOR-swizzled chunks.
// Gather: wave w accumulates ah rows w*8..w*8+7 in registers (lane owns 2 cols).
__global__ __launch_bounds__(512, 4) void k_fused(const int* __restrict__ deg,
    const int* __restrict__ col, const float* __restrict__ hin, float* __restrict__ hout,
    const u16* __restrict__ Bhi, const u16* __restrict__ Blo,
    const float* __restrict__ bih, const float* __restrict__ bhh, int apply_relu){
  __shared__ u16 Ahi[64*256];
  __shared__ u16 Alo[64*256];
  const int tid = threadIdx.x, lane = tid & 63, w = tid >> 6;   // w in 0..7
  const int tile = blockIdx.x * 64;

  // stage h-half (cols 128..255) from hin
#pragma unroll
  for (int i = 0; i < 4; ++i){
    int f = i*512 + tid;                   // 0..2047 ; 32 float4 per row
    int row = f >> 5, colq = f & 31;
    int n = tile + row;
    float4 v = {0.f,0.f,0.f,0.f};
    if (n < NN) v = *(const float4*)(hin + (size_t)n*128 + colq*4);
    int colu = 128 + colq*4;
    int chunk = colu >> 3, e4 = colu & 7;
    int cs = chunk ^ (row & 7);
    int idx = row*256 + cs*8 + e4;
    _Float16 h0=(_Float16)v.x, h1=(_Float16)v.y, h2=(_Float16)v.z, h3=(_Float16)v.w;
    _Float16 l0=(_Float16)(v.x-(float)h0), l1=(_Float16)(v.y-(float)h1),
             l2=(_Float16)(v.z-(float)h2), l3=(_Float16)(v.w-(float)h3);
    half4 hv = {h0,h1,h2,h3};
    half4 lv = {l0,l1,l2,l3};
    *(half4*)(Ahi + idx) = hv;
    *(half4*)(Alo + idx) = lv;
  }

  // gather ah-half (cols 0..127): wave w handles rows w*8 .. w*8+7
#pragma unroll 2
  for (int rr = 0; rr < 8; ++rr){
    int row = w*8 + rr;
    int node = tile + row;
    float ax = 0.f, ay = 0.f;
    if (node < NN){
      int d = deg[node]; d = min(d, MAXDEG);
      int mysrc = col[(size_t)node*MAXDEG + lane];
      for (int s = 0; s < d; ++s){
        int src = __shfl(mysrc, s, 64);
        float2 v = *(const float2*)(hin + (size_t)src*128 + (lane<<1));
        ax += v.x; ay += v.y;
      }
    }
    int colu = lane << 1;                  // even: pair stays inside one 8-chunk
    int chunk = colu >> 3;
    int cs = chunk ^ (row & 7);
    int idx = row*256 + cs*8 + (colu & 7);
    _Float16 hx=(_Float16)ax, hy=(_Float16)ay;
    _Float16 lx=(_Float16)(ax-(float)hx), ly=(_Float16)(ay-(float)hy);
    Ahi[idx]   = *(const u16*)&hx;  Ahi[idx+1] = *(const u16*)&hy;
    Alo[idx]   = *(const u16*)&lx;  Alo[idx+1] = *(const u16*)&ly;
  }
  __syncthreads();

  const f32x4 fz = {0.f,0.f,0.f,0.f};
  f32x4 acc[4][4];
#pragma unroll
  for (int g=0;g<4;++g)
#pragma unroll
    for (int R=0;R<4;++R) acc[g][R] = fz;

#pragma unroll
  for (int kk = 0; kk < 8; ++kk){
    f16x8 a_hi[4], a_lo[4];
#pragma unroll
    for (int R=0;R<4;++R){
      int arow = R*16 + (lane&15);
      int cs = (kk*4 + (lane>>4)) ^ (arow & 7);
      a_hi[R] = *(const f16x8*)(Ahi + arow*256 + cs*8);
      a_lo[R] = *(const f16x8*)(Alo + arow*256 + cs*8);
    }
#pragma unroll
    for (int g=0; g<4; ++g){
      if (g==2 && kk>=4) continue;   // inn: K[0,128) only
      if (g==3 && kk<4) continue;    // hn : K[128,256) only
      int colg = g*128 + w*16 + (lane&15);
      size_t boff = (((size_t)kk*512 + colg)*4 + (lane>>4))*8;
      f16x8 bh = *(const f16x8*)(Bhi + boff);
      f16x8 bl = *(const f16x8*)(Blo + boff);
#pragma unroll
      for (int R=0;R<4;++R){
        acc[g][R] = mfma16h(a_hi[R], bh, acc[g][R]);
        acc[g][R] = mfma16h(a_hi[R], bl, acc[g][R]);
        acc[g][R] = mfma16h(a_lo[R], bh, acc[g][R]);
      }
    }
  }

  {
    int jj = w*16 + (lane&15);
    float br  = bih[jj]     + bhh[jj];
    float bz  = bih[128+jj] + bhh[128+jj];
    float bin = bih[256+jj];
    float bhn = bhh[256+jj];
#pragma unroll
    for (int R=0;R<4;++R)
#pragma unroll
      for (int v=0;v<4;++v){
        int r_ = R*16 + ((lane>>4)<<2) + v;
        int n = tile + r_;
        float rg = sigm(acc[0][R][v] + br);
        float zg = sigm(acc[1][R][v] + bz);
        float hnv = acc[3][R][v] + bhn;
        float ng = tanh_(acc[2][R][v] + bin + rg*hnv);
        int colu = 128 + jj;
        int cs = (colu >> 3) ^ (r_ & 7);
        int lidx = r_*256 + cs*8 + (colu & 7);
        float hold = (float)(*(const _Float16*)(Ahi + lidx))
                   + (float)(*(const _Float16*)(Alo + lidx));
        float hnew = (1.f - zg)*ng + zg*hold;
        if (apply_relu) hnew = fmaxf(hnew, 0.f);
        if (n < NN) hout[(size_t)n*128 + jj] = hnew;
      }
  }
}

// ---------------- head: fp32, 8 nodes/block (unchanged) ----------------
__global__ __launch_bounds__(64) void k_head_n(const float* __restrict__ h,
    const float* __restrict__ l1, const float* __restrict__ b1,
    const float* __restrict__ l2, const float* __restrict__ b2, float* __restrict__ nodeout){
  int n0 = blockIdx.x * 8, j = threadIdx.x;
  __shared__ float hrow[8][128], t[8][64];
  for (int q = j; q < 1024; q += 64){
    int p = q >> 7, k = q & 127;
    hrow[p][k] = h[(size_t)(n0+p)*128 + k];
  }
  __syncthreads();
  float s[8];
#pragma unroll
  for (int p=0;p<8;++p) s[p] = b1[j];
  for (int k=0;k<128;++k){
    float w = l1[k*64 + j];
#pragma unroll
    for (int p=0;p<8;++p) s[p] = fmaf(hrow[p][k], w, s[p]);
  }
#pragma unroll
  for (int p=0;p<8;++p) t[p][j] = fmaxf(s[p], 0.f);
  __syncthreads();
  int c = j & 15;
#pragma unroll
  for (int pp=0;pp<2;++pp){
    int p = (j >> 4) + pp*4;
    float o = b2[c];
    for (int k=0;k<64;++k) o = fmaf(t[p][k], l2[k*16 + c], o);
    nodeout[(size_t)(n0+p)*16 + c] = o;
  }
}

// ---------------- per-graph readout: segmented reduce (batch is sorted) ----------------
__device__ __forceinline__ int lbound32(const int* __restrict__ a, int n, int v){
  int lo = 0, hi = n;
  while (lo < hi){ int mid = (lo+hi)>>1; if (a[mid] < v) lo = mid+1; else hi = mid; }
  return lo;
}
__device__ __forceinline__ int lbound64(const i64* __restrict__ a, int n, i64 v){
  int lo = 0, hi = n;
  while (lo < hi){ int mid = (lo+hi)>>1; if (a[mid] < v) lo = mid+1; else hi = mid; }
  return lo;
}
__global__ __launch_bounds__(256) void k_reduce(const float* __restrict__ nodeout,
    const int* __restrict__ batch, const int* __restrict__ flags, float* __restrict__ out){
  int g = blockIdx.x;
  int lo, hi;
  if (flags[1]){
    const i64* b64 = (const i64*)batch;
    lo = lbound64(b64, NN, (i64)g); hi = lbound64(b64, NN, (i64)g+1);
  } else {
    lo = lbound32(batch, NN, g); hi = lbound32(batch, NN, g+1);
  }
  int tid = threadIdx.x;
  int c = tid & 15, rr = tid >> 4;
  float s = 0.f;
  for (int r = lo + rr; r < hi; r += 16) s += nodeout[(size_t)r*16 + c];
  __shared__ float red[256];
  red[tid] = s; __syncthreads();
  for (int step = 128; step >= 16; step >>= 1){
    if (tid < step) red[tid] += red[tid + step];
    __syncthreads();
  }
  if (tid < 16) out[g*16 + tid] = red[tid];
}

// ---------------- launch ----------------
extern "C" void kernel_launch(void* const* d_in, const int* in_sizes, int n_in,
                              void* d_out, int out_size, void* d_ws, size_t ws_size,
                              hipStream_t stream){
  const float* x        = (const float*)d_in[0];
  const float* pos      = (const float*)d_in[1];
  const int*   edge     = (const int*)d_in[2];
  const int*   batch    = (const int*)d_in[3];
  const float* node_w1  = (const float*)d_in[4];
  const float* node_b1  = (const float*)d_in[5];
  const float* node_w2  = (const float*)d_in[6];
  const float* node_b2  = (const float*)d_in[7];
  const float* conv_w   = (const float*)d_in[8];
  const float* gru_wih  = (const float*)d_in[9];
  const float* gru_whh  = (const float*)d_in[10];
  const float* gru_bih  = (const float*)d_in[11];
  const float* gru_bhh  = (const float*)d_in[12];
  const float* lin1_w   = (const float*)d_in[13];
  const float* lin1_b   = (const float*)d_in[14];
  const float* lin2_w   = (const float*)d_in[15];
  const float* lin2_b   = (const float*)d_in[16];
  float* out = (float*)d_out;

  char* p = (char*)d_ws;
  int*   flags = (int*)p;   p += 256;
  float* h0    = (float*)p; p += (size_t)NN*128*4;
  float* h1    = (float*)p; p += (size_t)NN*128*4;   // ping-pong partner (was ah)
  float* nodeout = (float*)p; p += (size_t)NN*16*4;
  int*   deg   = (int*)p;   p += (size_t)NN*4;
  int*   col   = (int*)p;   p += (size_t)NN*MAXDEG*4;
  float* wihT  = (float*)p; p += (size_t)3*49152*4;
  float* whhT  = (float*)p; p += (size_t)3*49152*4;
  float* WeffT = (float*)p; p += (size_t)9*49152*4;
  u16*   Bhi   = (u16*)p;   p += (size_t)9*512*256*2;
  u16*   Blo   = (u16*)p;   p += (size_t)9*512*256*2;

  k_detect<<<1, 512, 0, stream>>>(edge, batch, flags);
  hipMemsetAsync(deg, 0, (size_t)NN*4, stream);
  k_prep_wT<<<(147456 + 255)/256, 256, 0, stream>>>(gru_wih, gru_whh, wihT, whhT);
  k_weff<<<9*128, 384, 0, stream>>>(conv_w, wihT, WeffT);
  k_bsplit<<<9*512*256/256, 256, 0, stream>>>(WeffT, whhT, Bhi, Blo);
  k_fill_edges<<<NE/256, 256, 0, stream>>>(edge, flags, deg, col);
  k_enc_n<<<NN/8, 128, 0, stream>>>(x, pos, node_w1, node_b1, node_w2, node_b2, h0);

  float* hbuf[2] = { h0, h1 };
  for (int l = 0; l < 3; ++l){
    for (int i = 0; i < 3; ++i){
      int li = l*3 + i;
      k_fused<<<(NN + 63)/64, 512, 0, stream>>>(deg, col, hbuf[li & 1], hbuf[(li + 1) & 1],
          Bhi + (size_t)li*131072, Blo + (size_t)li*131072,
          gru_bih + l*384, gru_bhh + l*384, (i==2) ? 1 : 0);
    }
  }
  k_head_n<<<NN/8, 64, 0, stream>>>(hbuf[1], lin1_w, lin1_b, lin2_w, lin2_b, nodeout);
  k_reduce<<<NG, 256, 0, stream>>>(nodeout, batch, flags, out);
}

// Round 8
// 2122.507 us; speedup vs baseline: 1.3504x; 1.3504x over previous
//
#include <hip/hip_runtime.h>

#define NN 100000
#define NE 1600000
#define NG 64
#define MAXDEG 64

typedef long long i64;
typedef unsigned short u16;
typedef unsigned int u32;
typedef __attribute__((ext_vector_type(8))) _Float16 f16x8;
typedef __attribute__((ext_vector_type(4))) _Float16 half4;
typedef __attribute__((ext_vector_type(4))) float f32x4;

__device__ __forceinline__ float sigm(float x){ return 1.f/(1.f+__expf(-x)); }
__device__ __forceinline__ float tanh_(float x){ return 2.f/(1.f+__expf(-2.f*x)) - 1.f; }
__device__ __forceinline__ f32x4 mfma16h(f16x8 a, f16x8 b, f32x4 c){
  return __builtin_amdgcn_mfma_f32_16x16x32_f16(a,b,c,0,0,0);
}
__device__ __forceinline__ u16 h2u(_Float16 h){ return *(const u16*)&h; }

// ---------------- int-width detection ----------------
__global__ __launch_bounds__(512) void k_detect(const int* __restrict__ ei,
    const int* __restrict__ batch, int* __restrict__ flags){
  int t = threadIdx.x;
  __shared__ int nz_e, nz_b;
  if (t == 0){ nz_e = 0; nz_b = 0; }
  __syncthreads();
  if (ei[2*t + 1] != 0) nz_e = 1;
  int k = NN/2 - 512 + t;
  if (batch[2*k + 1] != 0) nz_b = 1;
  __syncthreads();
  if (t == 0){ flags[0] = nz_e ? 0 : 1; flags[1] = nz_b ? 0 : 1; }
}

// ---------------- transposed GRU weights: wT[l][k][jc] = w[l][jc][k] ----------------
__global__ __launch_bounds__(256) void k_prep_wT(const float* __restrict__ wih,
    const float* __restrict__ whh, float* __restrict__ wihT, float* __restrict__ whhT){
  int idx = blockIdx.x*256 + threadIdx.x;            // 3*49152 = 147456
  if (idx >= 3*49152) return;
  int l = idx/49152, r = idx - l*49152, k = r/384, jc = r - k*384;
  wihT[idx] = wih[((size_t)l*384 + jc)*128 + k];
  whhT[idx] = whh[((size_t)l*384 + jc)*128 + k];
}

// ---------------- Weff fold: WeffT[li][k][jc] = sum_m cw[li][k][m] * wih[l][jc][m] ----------------
__global__ __launch_bounds__(384) void k_weff(const float* __restrict__ convw,
    const float* __restrict__ wihT, float* __restrict__ WeffT){
  int bid = blockIdx.x;               // 9*128
  int li = bid >> 7, k = bid & 127;
  int l = li / 3;
  int j = threadIdx.x;                // 0..383
  __shared__ float cwrow[128];
  if (j < 128) cwrow[j] = convw[((size_t)li*128 + k)*128 + j];
  __syncthreads();
  const float* wT = wihT + (size_t)l*49152;
  float acc = 0.f;
#pragma unroll 8
  for (int m = 0; m < 128; ++m)
    acc = fmaf(cwrow[m], wT[(size_t)m*384 + j], acc);
  WeffT[(size_t)li*49152 + (size_t)k*384 + j] = acc;
}

// ---------------- split fp16 B planes, MFMA-fragment-contiguous layout ----------------
__global__ __launch_bounds__(256) void k_bsplit(const float* __restrict__ WeffT,
    const float* __restrict__ whhT, u16* __restrict__ Bhi, u16* __restrict__ Blo){
  int idx = blockIdx.x*256 + threadIdx.x;   // 9*512*256 exact
  int li = idx >> 17;
  int r = idx & 131071;
  int col = r >> 8, k = r & 255;
  int l = li / 3;
  float v = 0.f;
  if (k < 128){
    if (col < 384) v = WeffT[(size_t)li*49152 + (size_t)k*384 + col];
  } else {
    int k2 = k - 128;
    if (col < 256)       v = whhT[(size_t)l*49152 + (size_t)k2*384 + col];
    else if (col >= 384) v = whhT[(size_t)l*49152 + (size_t)k2*384 + (col-128)];
  }
  _Float16 hi = (_Float16)v;
  _Float16 lo = (_Float16)(v - (float)hi);
  size_t widx = (size_t)li*131072 + ((((size_t)(k>>5))*512 + col)*4 + ((k>>3)&3))*8 + (k&7);
  Bhi[widx] = h2u(hi);
  Blo[widx] = h2u(lo);
}

// ---------------- padded adjacency by dst ----------------
__global__ __launch_bounds__(256) void k_fill_edges(const int* __restrict__ ei,
    const int* __restrict__ flags, int* __restrict__ deg, int* __restrict__ col){
  int e = blockIdx.x*256 + threadIdx.x;
  if (e >= NE) return;
  int s, d;
  if (flags[0]){
    const i64* e64 = (const i64*)ei;
    s = (int)e64[e]; d = (int)e64[NE + e];
  } else {
    s = ei[e]; d = ei[NE + e];
  }
  int slot = atomicAdd(&deg[d], 1);
  if (slot < MAXDEG) col[(size_t)d*MAXDEG + slot] = s;
}

// ---------------- encoder: fp32, 8 nodes/block (unchanged, proven) ----------------
__global__ __launch_bounds__(128) void k_enc_n(const float* __restrict__ x,
    const float* __restrict__ pos, const float* __restrict__ w1, const float* __restrict__ b1,
    const float* __restrict__ w2, const float* __restrict__ b2, float* __restrict__ h){
  int n0 = blockIdx.x * 8, j = threadIdx.x;
  __shared__ float xr[8][68];
  __shared__ float t1[8][128];
  for (int q = j; q < 8*67; q += 128){
    int p = q/67, kk = q - p*67;
    xr[p][kk] = (kk < 64) ? x[(size_t)(n0+p)*64 + kk] : pos[(size_t)(n0+p)*3 + (kk-64)];
  }
  __syncthreads();
  float s[8];
#pragma unroll
  for (int p=0;p<8;++p) s[p] = b1[j];
  for (int k=0;k<67;++k){
    float w = w1[k*128 + j];
#pragma unroll
    for (int p=0;p<8;++p) s[p] = fmaf(xr[p][k], w, s[p]);
  }
#pragma unroll
  for (int p=0;p<8;++p) t1[p][j] = fmaxf(s[p], 0.f);
  __syncthreads();
#pragma unroll
  for (int p=0;p<8;++p) s[p] = b2[j];
  for (int k=0;k<128;++k){
    float w = w2[k*128 + j];
#pragma unroll
    for (int p=0;p<8;++p) s[p] = fmaf(t1[p][k], w, s[p]);
  }
#pragma unroll
  for (int p=0;p<8;++p) h[(size_t)(n0+p)*128 + j] = s[p];
}

// ---------------- FUSED v2: gather + split-fp16 3-pass MFMA GRU ----------------
// 32-row tile (LDS 32KB -> 4 blocks/CU), 8 waves, R=2, forced <=64 VGPR.
// LDS A = [ah | h] (K=256) hi/lo fp16, XOR-swizzled 8-elt chunks.
__global__ __launch_bounds__(512, 8) void k_fused(const int* __restrict__ deg,
    const int* __restrict__ col, const float* __restrict__ hin, float* __restrict__ hout,
    const u16* __restrict__ Bhi, const u16* __restrict__ Blo,
    const float* __restrict__ bih, const float* __restrict__ bhh, int apply_relu){
  __shared__ u16 Ahi[32*256];
  __shared__ u16 Alo[32*256];
  const int tid = threadIdx.x, lane = tid & 63, w = tid >> 6;   // w in 0..7
  const int tile = blockIdx.x * 32;                             // 3125*32 = NN exact

  // stage h-half (cols 128..255): 32 rows x 32 float4 = 1024; 2 per thread
#pragma unroll
  for (int i = 0; i < 2; ++i){
    int f = i*512 + tid;
    int row = f >> 5, colq = f & 31;
    float4 v = *(const float4*)(hin + (size_t)(tile+row)*128 + colq*4);
    int colu = 128 + colq*4;
    int cs = (colu >> 3) ^ (row & 7);
    int idx = row*256 + cs*8 + (colu & 7);
    _Float16 h0=(_Float16)v.x, h1=(_Float16)v.y, h2=(_Float16)v.z, h3=(_Float16)v.w;
    _Float16 l0=(_Float16)(v.x-(float)h0), l1=(_Float16)(v.y-(float)h1),
             l2=(_Float16)(v.z-(float)h2), l3=(_Float16)(v.w-(float)h3);
    half4 hv = {h0,h1,h2,h3};
    half4 lv = {l0,l1,l2,l3};
    *(half4*)(Ahi + idx) = hv;
    *(half4*)(Alo + idx) = lv;
  }

  // gather ah-half (cols 0..127): wave w owns rows w*4 .. w*4+3; lane owns 2 cols
#pragma unroll
  for (int rr = 0; rr < 4; ++rr){
    int row = w*4 + rr;
    int node = tile + row;
    float ax = 0.f, ay = 0.f;
    int d = deg[node]; d = min(d, MAXDEG);
    int mysrc = col[(size_t)node*MAXDEG + lane];
    int s = 0;
    for (; s + 1 < d; s += 2){
      int s0 = __shfl(mysrc, s, 64);
      int s1 = __shfl(mysrc, s+1, 64);
      float2 v0 = *(const float2*)(hin + (size_t)s0*128 + (lane<<1));
      float2 v1 = *(const float2*)(hin + (size_t)s1*128 + (lane<<1));
      ax += v0.x + v1.x;
      ay += v0.y + v1.y;
    }
    if (s < d){
      int s0 = __shfl(mysrc, s, 64);
      float2 v0 = *(const float2*)(hin + (size_t)s0*128 + (lane<<1));
      ax += v0.x; ay += v0.y;
    }
    int colu = lane << 1;                  // even -> u32-aligned pair in one chunk
    int cs = (colu >> 3) ^ (row & 7);
    int idx = row*256 + cs*8 + (colu & 7);
    _Float16 hx=(_Float16)ax, hy=(_Float16)ay;
    _Float16 lx=(_Float16)(ax-(float)hx), ly=(_Float16)(ay-(float)hy);
    *(u32*)(Ahi + idx) = (u32)h2u(hx) | ((u32)h2u(hy) << 16);
    *(u32*)(Alo + idx) = (u32)h2u(lx) | ((u32)h2u(ly) << 16);
  }
  __syncthreads();

  const f32x4 fz = {0.f,0.f,0.f,0.f};
  f32x4 acc[4][2];
#pragma unroll
  for (int g=0;g<4;++g)
#pragma unroll
    for (int R=0;R<2;++R) acc[g][R] = fz;

#pragma unroll
  for (int kk = 0; kk < 8; ++kk){
    f16x8 a_hi[2], a_lo[2];
#pragma unroll
    for (int R=0;R<2;++R){
      int arow = R*16 + (lane&15);
      int cs = (kk*4 + (lane>>4)) ^ (arow & 7);
      a_hi[R] = *(const f16x8*)(Ahi + arow*256 + cs*8);
      a_lo[R] = *(const f16x8*)(Alo + arow*256 + cs*8);
    }
#pragma unroll
    for (int g=0; g<4; ++g){
      if (g==2 && kk>=4) continue;   // inn: K[0,128) only
      if (g==3 && kk<4) continue;    // hn : K[128,256) only
      int colg = g*128 + w*16 + (lane&15);
      size_t boff = (((size_t)kk*512 + colg)*4 + (lane>>4))*8;
      f16x8 bh = *(const f16x8*)(Bhi + boff);
      f16x8 bl = *(const f16x8*)(Blo + boff);
#pragma unroll
      for (int R=0;R<2;++R){
        acc[g][R] = mfma16h(a_hi[R], bh, acc[g][R]);
        acc[g][R] = mfma16h(a_hi[R], bl, acc[g][R]);
        acc[g][R] = mfma16h(a_lo[R], bh, acc[g][R]);
      }
    }
  }

  {
    int jj = w*16 + (lane&15);
    float br  = bih[jj]     + bhh[jj];
    float bz  = bih[128+jj] + bhh[128+jj];
    float bin = bih[256+jj];
    float bhn = bhh[256+jj];
#pragma unroll
    for (int R=0;R<2;++R)
#pragma unroll
      for (int v=0;v<4;++v){
        int r_ = R*16 + ((lane>>4)<<2) + v;
        float rg = sigm(acc[0][R][v] + br);
        float zg = sigm(acc[1][R][v] + bz);
        float hnv = acc[3][R][v] + bhn;
        float ng = tanh_(acc[2][R][v] + bin + rg*hnv);
        int colu = 128 + jj;
        int cs = (colu >> 3) ^ (r_ & 7);
        int lidx = r_*256 + cs*8 + (colu & 7);
        float hold = (float)(*(const _Float16*)(Ahi + lidx))
                   + (float)(*(const _Float16*)(Alo + lidx));
        float hnew = (1.f - zg)*ng + zg*hold;
        if (apply_relu) hnew = fmaxf(hnew, 0.f);
        hout[(size_t)(tile + r_)*128 + jj] = hnew;
      }
  }
}

// ---------------- head: fp32, 8 nodes/block (unchanged) ----------------
__global__ __launch_bounds__(64) void k_head_n(const float* __restrict__ h,
    const float* __restrict__ l1, const float* __restrict__ b1,
    const float* __restrict__ l2, const float* __restrict__ b2, float* __restrict__ nodeout){
  int n0 = blockIdx.x * 8, j = threadIdx.x;
  __shared__ float hrow[8][128], t[8][64];
  for (int q = j; q < 1024; q += 64){
    int p = q >> 7, k = q & 127;
    hrow[p][k] = h[(size_t)(n0+p)*128 + k];
  }
  __syncthreads();
  float s[8];
#pragma unroll
  for (int p=0;p<8;++p) s[p] = b1[j];
  for (int k=0;k<128;++k){
    float w = l1[k*64 + j];
#pragma unroll
    for (int p=0;p<8;++p) s[p] = fmaf(hrow[p][k], w, s[p]);
  }
#pragma unroll
  for (int p=0;p<8;++p) t[p][j] = fmaxf(s[p], 0.f);
  __syncthreads();
  int c = j & 15;
#pragma unroll
  for (int pp=0;pp<2;++pp){
    int p = (j >> 4) + pp*4;
    float o = b2[c];
    for (int k=0;k<64;++k) o = fmaf(t[p][k], l2[k*16 + c], o);
    nodeout[(size_t)(n0+p)*16 + c] = o;
  }
}

// ---------------- per-graph readout: segmented reduce (batch is sorted) ----------------
__device__ __forceinline__ int lbound32(const int* __restrict__ a, int n, int v){
  int lo = 0, hi = n;
  while (lo < hi){ int mid = (lo+hi)>>1; if (a[mid] < v) lo = mid+1; else hi = mid; }
  return lo;
}
__device__ __forceinline__ int lbound64(const i64* __restrict__ a, int n, i64 v){
  int lo = 0, hi = n;
  while (lo < hi){ int mid = (lo+hi)>>1; if (a[mid] < v) lo = mid+1; else hi = mid; }
  return lo;
}
__global__ __launch_bounds__(256) void k_reduce(const float* __restrict__ nodeout,
    const int* __restrict__ batch, const int* __restrict__ flags, float* __restrict__ out){
  int g = blockIdx.x;
  int lo, hi;
  if (flags[1]){
    const i64* b64 = (const i64*)batch;
    lo = lbound64(b64, NN, (i64)g); hi = lbound64(b64, NN, (i64)g+1);
  } else {
    lo = lbound32(batch, NN, g); hi = lbound32(batch, NN, g+1);
  }
  int tid = threadIdx.x;
  int c = tid & 15, rr = tid >> 4;
  float s = 0.f;
  for (int r = lo + rr; r < hi; r += 16) s += nodeout[(size_t)r*16 + c];
  __shared__ float red[256];
  red[tid] = s; __syncthreads();
  for (int step = 128; step >= 16; step >>= 1){
    if (tid < step) red[tid] += red[tid + step];
    __syncthreads();
  }
  if (tid < 16) out[g*16 + tid] = red[tid];
}

// ---------------- launch ----------------
extern "C" void kernel_launch(void* const* d_in, const int* in_sizes, int n_in,
                              void* d_out, int out_size, void* d_ws, size_t ws_size,
                              hipStream_t stream){
  const float* x        = (const float*)d_in[0];
  const float* pos      = (const float*)d_in[1];
  const int*   edge     = (const int*)d_in[2];
  const int*   batch    = (const int*)d_in[3];
  const float* node_w1  = (const float*)d_in[4];
  const float* node_b1  = (const float*)d_in[5];
  const float* node_w2  = (const float*)d_in[6];
  const float* node_b2  = (const float*)d_in[7];
  const float* conv_w   = (const float*)d_in[8];
  const float* gru_wih  = (const float*)d_in[9];
  const float* gru_whh  = (const float*)d_in[10];
  const float* gru_bih  = (const float*)d_in[11];
  const float* gru_bhh  = (const float*)d_in[12];
  const float* lin1_w   = (const float*)d_in[13];
  const float* lin1_b   = (const float*)d_in[14];
  const float* lin2_w   = (const float*)d_in[15];
  const float* lin2_b   = (const float*)d_in[16];
  float* out = (float*)d_out;

  char* p = (char*)d_ws;
  int*   flags = (int*)p;   p += 256;
  float* h0    = (float*)p; p += (size_t)NN*128*4;
  float* h1    = (float*)p; p += (size_t)NN*128*4;   // ping-pong partner
  float* nodeout = (float*)p; p += (size_t)NN*16*4;
  int*   deg   = (int*)p;   p += (size_t)NN*4;
  int*   col   = (int*)p;   p += (size_t)NN*MAXDEG*4;
  float* wihT  = (float*)p; p += (size_t)3*49152*4;
  float* whhT  = (float*)p; p += (size_t)3*49152*4;
  float* WeffT = (float*)p; p += (size_t)9*49152*4;
  u16*   Bhi   = (u16*)p;   p += (size_t)9*512*256*2;
  u16*   Blo   = (u16*)p;   p += (size_t)9*512*256*2;

  k_detect<<<1, 512, 0, stream>>>(edge, batch, flags);
  hipMemsetAsync(deg, 0, (size_t)NN*4, stream);
  k_prep_wT<<<(147456 + 255)/256, 256, 0, stream>>>(gru_wih, gru_whh, wihT, whhT);
  k_weff<<<9*128, 384, 0, stream>>>(conv_w, wihT, WeffT);
  k_bsplit<<<9*512*256/256, 256, 0, stream>>>(WeffT, whhT, Bhi, Blo);
  k_fill_edges<<<NE/256, 256, 0, stream>>>(edge, flags, deg, col);
  k_enc_n<<<NN/8, 128, 0, stream>>>(x, pos, node_w1, node_b1, node_w2, node_b2, h0);

  float* hbuf[2] = { h0, h1 };
  for (int l = 0; l < 3; ++l){
    for (int i = 0; i < 3; ++i){
      int li = l*3 + i;
      k_fused<<<NN/32, 512, 0, stream>>>(deg, col, hbuf[li & 1], hbuf[(li + 1) & 1],
          Bhi + (size_t)li*131072, Blo + (size_t)li*131072,
          gru_bih + l*384, gru_bhh + l*384, (i==2) ? 1 : 0);
    }
  }
  k_head_n<<<NN/8, 64, 0, stream>>>(hbuf[1], lin1_w, lin1_b, lin2_w, lin2_b, nodeout);
  k_reduce<<<NG, 256, 0, stream>>>(nodeout, batch, flags, out);
}

// Round 9
// 2022.691 us; speedup vs baseline: 1.4171x; 1.0493x over previous
//
#include <hip/hip_runtime.h>

#define NN 100000
#define NE 1600000
#define NG 64
#define MAXDEG 64

typedef long long i64;
typedef unsigned short u16;
typedef unsigned int u32;
typedef __attribute__((ext_vector_type(8))) _Float16 f16x8;
typedef __attribute__((ext_vector_type(4))) _Float16 half4;
typedef __attribute__((ext_vector_type(4))) float f32x4;

__device__ __forceinline__ float sigm(float x){ return 1.f/(1.f+__expf(-x)); }
__device__ __forceinline__ float tanh_(float x){ return 2.f/(1.f+__expf(-2.f*x)) - 1.f; }
__device__ __forceinline__ f32x4 mfma16h(f16x8 a, f16x8 b, f32x4 c){
  return __builtin_amdgcn_mfma_f32_16x16x32_f16(a,b,c,0,0,0);
}
__device__ __forceinline__ u16 h2u(_Float16 h){ return *(const u16*)&h; }

// ---------------- int-width detection ----------------
__global__ __launch_bounds__(512) void k_detect(const int* __restrict__ ei,
    const int* __restrict__ batch, int* __restrict__ flags){
  int t = threadIdx.x;
  __shared__ int nz_e, nz_b;
  if (t == 0){ nz_e = 0; nz_b = 0; }
  __syncthreads();
  if (ei[2*t + 1] != 0) nz_e = 1;
  int k = NN/2 - 512 + t;
  if (batch[2*k + 1] != 0) nz_b = 1;
  __syncthreads();
  if (t == 0){ flags[0] = nz_e ? 0 : 1; flags[1] = nz_b ? 0 : 1; }
}

// ---------------- transposed GRU weights: wT[l][k][jc] = w[l][jc][k] ----------------
__global__ __launch_bounds__(256) void k_prep_wT(const float* __restrict__ wih,
    const float* __restrict__ whh, float* __restrict__ wihT, float* __restrict__ whhT){
  int idx = blockIdx.x*256 + threadIdx.x;            // 3*49152 = 147456
  if (idx >= 3*49152) return;
  int l = idx/49152, r = idx - l*49152, k = r/384, jc = r - k*384;
  wihT[idx] = wih[((size_t)l*384 + jc)*128 + k];
  whhT[idx] = whh[((size_t)l*384 + jc)*128 + k];
}

// ---------------- Weff fold: WeffT[li][k][jc] = sum_m cw[li][k][m] * wih[l][jc][m] ----------------
__global__ __launch_bounds__(384) void k_weff(const float* __restrict__ convw,
    const float* __restrict__ wihT, float* __restrict__ WeffT){
  int bid = blockIdx.x;               // 9*128
  int li = bid >> 7, k = bid & 127;
  int l = li / 3;
  int j = threadIdx.x;                // 0..383
  __shared__ float cwrow[128];
  if (j < 128) cwrow[j] = convw[((size_t)li*128 + k)*128 + j];
  __syncthreads();
  const float* wT = wihT + (size_t)l*49152;
  float acc = 0.f;
#pragma unroll 8
  for (int m = 0; m < 128; ++m)
    acc = fmaf(cwrow[m], wT[(size_t)m*384 + j], acc);
  WeffT[(size_t)li*49152 + (size_t)k*384 + j] = acc;
}

// ---------------- split fp16 B planes, MFMA-fragment-contiguous layout ----------------
__global__ __launch_bounds__(256) void k_bsplit(const float* __restrict__ WeffT,
    const float* __restrict__ whhT, u16* __restrict__ Bhi, u16* __restrict__ Blo){
  int idx = blockIdx.x*256 + threadIdx.x;   // 9*512*256 exact
  int li = idx >> 17;
  int r = idx & 131071;
  int col = r >> 8, k = r & 255;
  int l = li / 3;
  float v = 0.f;
  if (k < 128){
    if (col < 384) v = WeffT[(size_t)li*49152 + (size_t)k*384 + col];
  } else {
    int k2 = k - 128;
    if (col < 256)       v = whhT[(size_t)l*49152 + (size_t)k2*384 + col];
    else if (col >= 384) v = whhT[(size_t)l*49152 + (size_t)k2*384 + (col-128)];
  }
  _Float16 hi = (_Float16)v;
  _Float16 lo = (_Float16)(v - (float)hi);
  size_t widx = (size_t)li*131072 + ((((size_t)(k>>5))*512 + col)*4 + ((k>>3)&3))*8 + (k&7);
  Bhi[widx] = h2u(hi);
  Blo[widx] = h2u(lo);
}

// ---------------- padded adjacency by dst ----------------
__global__ __launch_bounds__(256) void k_fill_edges(const int* __restrict__ ei,
    const int* __restrict__ flags, int* __restrict__ deg, int* __restrict__ col){
  int e = blockIdx.x*256 + threadIdx.x;
  if (e >= NE) return;
  int s, d;
  if (flags[0]){
    const i64* e64 = (const i64*)ei;
    s = (int)e64[e]; d = (int)e64[NE + e];
  } else {
    s = ei[e]; d = ei[NE + e];
  }
  int slot = atomicAdd(&deg[d], 1);
  if (slot < MAXDEG) col[(size_t)d*MAXDEG + slot] = s;
}

// ---------------- encoder: fp32, 8 nodes/block (unchanged, proven) ----------------
__global__ __launch_bounds__(128) void k_enc_n(const float* __restrict__ x,
    const float* __restrict__ pos, const float* __restrict__ w1, const float* __restrict__ b1,
    const float* __restrict__ w2, const float* __restrict__ b2, float* __restrict__ h){
  int n0 = blockIdx.x * 8, j = threadIdx.x;
  __shared__ float xr[8][68];
  __shared__ float t1[8][128];
  for (int q = j; q < 8*67; q += 128){
    int p = q/67, kk = q - p*67;
    xr[p][kk] = (kk < 64) ? x[(size_t)(n0+p)*64 + kk] : pos[(size_t)(n0+p)*3 + (kk-64)];
  }
  __syncthreads();
  float s[8];
#pragma unroll
  for (int p=0;p<8;++p) s[p] = b1[j];
  for (int k=0;k<67;++k){
    float w = w1[k*128 + j];
#pragma unroll
    for (int p=0;p<8;++p) s[p] = fmaf(xr[p][k], w, s[p]);
  }
#pragma unroll
  for (int p=0;p<8;++p) t1[p][j] = fmaxf(s[p], 0.f);
  __syncthreads();
#pragma unroll
  for (int p=0;p<8;++p) s[p] = b2[j];
  for (int k=0;k<128;++k){
    float w = w2[k*128 + j];
#pragma unroll
    for (int p=0;p<8;++p) s[p] = fmaf(t1[p][k], w, s[p]);
  }
#pragma unroll
  for (int p=0;p<8;++p) h[(size_t)(n0+p)*128 + j] = s[p];
}

// ---------------- FUSED v3: gather + split-fp16 3-pass MFMA GRU ----------------
// 32-row tile, 8 waves, LDS 32KB. Gather: 2 rows/wave, float4 per 32-lane half.
// Epilogue: LDS-staged coalesced float4 stores.
__global__ __launch_bounds__(512, 8) void k_fused(const int* __restrict__ deg,
    const int* __restrict__ col, const float* __restrict__ hin, float* __restrict__ hout,
    const u16* __restrict__ Bhi, const u16* __restrict__ Blo,
    const float* __restrict__ bih, const float* __restrict__ bhh, int apply_relu){
  __shared__ u16 Ahi[32*256];
  __shared__ u16 Alo[32*256];
  const int tid = threadIdx.x, lane = tid & 63, w = tid >> 6;   // w in 0..7
  const int tile = blockIdx.x * 32;                             // 3125*32 = NN exact

  // stage h-half (cols 128..255): 32 rows x 32 float4 = 1024; 2 per thread
#pragma unroll
  for (int i = 0; i < 2; ++i){
    int f = i*512 + tid;
    int row = f >> 5, colq = f & 31;
    float4 v = *(const float4*)(hin + (size_t)(tile+row)*128 + colq*4);
    int colu = 128 + colq*4;
    int cs = (colu >> 3) ^ (row & 7);
    int idx = row*256 + cs*8 + (colu & 7);
    _Float16 h0=(_Float16)v.x, h1=(_Float16)v.y, h2=(_Float16)v.z, h3=(_Float16)v.w;
    _Float16 l0=(_Float16)(v.x-(float)h0), l1=(_Float16)(v.y-(float)h1),
             l2=(_Float16)(v.z-(float)h2), l3=(_Float16)(v.w-(float)h3);
    half4 hv = {h0,h1,h2,h3};
    half4 lv = {l0,l1,l2,l3};
    *(half4*)(Ahi + idx) = hv;
    *(half4*)(Alo + idx) = lv;
  }

  // gather ah-half (cols 0..127): 2 rows per wave per pass; lane-half owns one row,
  // ln32 covers 128 cols as float4. Per-column sum order = slot order (unchanged).
  const int half = lane >> 5, ln32 = lane & 31;
#pragma unroll
  for (int rr = 0; rr < 2; ++rr){
    int row = rr*16 + w*2 + half;
    int node = tile + row;
    int d = deg[node]; d = min(d, MAXDEG);
    int src1 = col[(size_t)node*MAXDEG + ln32];
    int src2 = col[(size_t)node*MAXDEG + 32 + ln32];
    float ax=0.f, ay=0.f, az=0.f, aw=0.f;
    int d1 = min(d, 32);
    int s = 0;
    for (; s + 1 < d1; s += 2){
      int a0 = __shfl(src1, half*32 + s, 64);
      int a1 = __shfl(src1, half*32 + s + 1, 64);
      float4 v0 = *(const float4*)(hin + (size_t)a0*128 + (ln32<<2));
      float4 v1 = *(const float4*)(hin + (size_t)a1*128 + (ln32<<2));
      ax += v0.x; ay += v0.y; az += v0.z; aw += v0.w;
      ax += v1.x; ay += v1.y; az += v1.z; aw += v1.w;
    }
    if (s < d1){
      int a0 = __shfl(src1, half*32 + s, 64);
      float4 v0 = *(const float4*)(hin + (size_t)a0*128 + (ln32<<2));
      ax += v0.x; ay += v0.y; az += v0.z; aw += v0.w;
    }
    int d2 = d - d1;
    s = 0;
    for (; s + 1 < d2; s += 2){
      int a0 = __shfl(src2, half*32 + s, 64);
      int a1 = __shfl(src2, half*32 + s + 1, 64);
      float4 v0 = *(const float4*)(hin + (size_t)a0*128 + (ln32<<2));
      float4 v1 = *(const float4*)(hin + (size_t)a1*128 + (ln32<<2));
      ax += v0.x; ay += v0.y; az += v0.z; aw += v0.w;
      ax += v1.x; ay += v1.y; az += v1.z; aw += v1.w;
    }
    if (s < d2){
      int a0 = __shfl(src2, half*32 + s, 64);
      float4 v0 = *(const float4*)(hin + (size_t)a0*128 + (ln32<<2));
      ax += v0.x; ay += v0.y; az += v0.z; aw += v0.w;
    }
    int colu = ln32 << 2;                  // multiple of 4 -> half4-aligned slot
    int cs = (colu >> 3) ^ (row & 7);
    int idx = row*256 + cs*8 + (colu & 7);
    _Float16 hx=(_Float16)ax, hy=(_Float16)ay, hz=(_Float16)az, hw=(_Float16)aw;
    _Float16 lx=(_Float16)(ax-(float)hx), ly=(_Float16)(ay-(float)hy),
             lz=(_Float16)(az-(float)hz), lw=(_Float16)(aw-(float)hw);
    half4 hv = {hx,hy,hz,hw};
    half4 lv = {lx,ly,lz,lw};
    *(half4*)(Ahi + idx) = hv;
    *(half4*)(Alo + idx) = lv;
  }
  __syncthreads();

  const f32x4 fz = {0.f,0.f,0.f,0.f};
  f32x4 acc[4][2];
#pragma unroll
  for (int g=0;g<4;++g)
#pragma unroll
    for (int R=0;R<2;++R) acc[g][R] = fz;

#pragma unroll
  for (int kk = 0; kk < 8; ++kk){
    f16x8 a_hi[2], a_lo[2];
#pragma unroll
    for (int R=0;R<2;++R){
      int arow = R*16 + (lane&15);
      int cs = (kk*4 + (lane>>4)) ^ (arow & 7);
      a_hi[R] = *(const f16x8*)(Ahi + arow*256 + cs*8);
      a_lo[R] = *(const f16x8*)(Alo + arow*256 + cs*8);
    }
#pragma unroll
    for (int g=0; g<4; ++g){
      if (g==2 && kk>=4) continue;   // inn: K[0,128) only
      if (g==3 && kk<4) continue;    // hn : K[128,256) only
      int colg = g*128 + w*16 + (lane&15);
      size_t boff = (((size_t)kk*512 + colg)*4 + (lane>>4))*8;
      f16x8 bh = *(const f16x8*)(Bhi + boff);
      f16x8 bl = *(const f16x8*)(Blo + boff);
#pragma unroll
      for (int R=0;R<2;++R){
        acc[g][R] = mfma16h(a_hi[R], bh, acc[g][R]);
        acc[g][R] = mfma16h(a_hi[R], bl, acc[g][R]);
        acc[g][R] = mfma16h(a_lo[R], bh, acc[g][R]);
      }
    }
  }

  // gate epilogue -> registers (reads Ahi/Alo for hold), then LDS-staged coalesced store
  float hn_reg[2][4];
  {
    int jj = w*16 + (lane&15);
    float br  = bih[jj]     + bhh[jj];
    float bz  = bih[128+jj] + bhh[128+jj];
    float bin = bih[256+jj];
    float bhn = bhh[256+jj];
#pragma unroll
    for (int R=0;R<2;++R)
#pragma unroll
      for (int v=0;v<4;++v){
        int r_ = R*16 + ((lane>>4)<<2) + v;
        float rg = sigm(acc[0][R][v] + br);
        float zg = sigm(acc[1][R][v] + bz);
        float hnv = acc[3][R][v] + bhn;
        float ng = tanh_(acc[2][R][v] + bin + rg*hnv);
        int colu = 128 + jj;
        int cs = (colu >> 3) ^ (r_ & 7);
        int lidx = r_*256 + cs*8 + (colu & 7);
        float hold = (float)(*(const _Float16*)(Ahi + lidx))
                   + (float)(*(const _Float16*)(Alo + lidx));
        float hnew = (1.f - zg)*ng + zg*hold;
        if (apply_relu) hnew = fmaxf(hnew, 0.f);
        hn_reg[R][v] = hnew;
      }
  }
  __syncthreads();
  float* fout = (float*)Ahi;               // reuse 16 KB as [32][128] f32
  {
    int jj = w*16 + (lane&15);
#pragma unroll
    for (int R=0;R<2;++R)
#pragma unroll
      for (int v=0;v<4;++v){
        int r_ = R*16 + ((lane>>4)<<2) + v;
        fout[r_*128 + jj] = hn_reg[R][v];
      }
  }
  __syncthreads();
#pragma unroll
  for (int i = 0; i < 2; ++i){
    int f = i*512 + tid;
    int row = f >> 5, colq = f & 31;
    float4 vv = *(const float4*)(fout + row*128 + colq*4);
    *(float4*)(hout + (size_t)(tile+row)*128 + colq*4) = vv;
  }
}

// ---------------- head: fp32, 8 nodes/block (unchanged) ----------------
__global__ __launch_bounds__(64) void k_head_n(const float* __restrict__ h,
    const float* __restrict__ l1, const float* __restrict__ b1,
    const float* __restrict__ l2, const float* __restrict__ b2, float* __restrict__ nodeout){
  int n0 = blockIdx.x * 8, j = threadIdx.x;
  __shared__ float hrow[8][128], t[8][64];
  for (int q = j; q < 1024; q += 64){
    int p = q >> 7, k = q & 127;
    hrow[p][k] = h[(size_t)(n0+p)*128 + k];
  }
  __syncthreads();
  float s[8];
#pragma unroll
  for (int p=0;p<8;++p) s[p] = b1[j];
  for (int k=0;k<128;++k){
    float w = l1[k*64 + j];
#pragma unroll
    for (int p=0;p<8;++p) s[p] = fmaf(hrow[p][k], w, s[p]);
  }
#pragma unroll
  for (int p=0;p<8;++p) t[p][j] = fmaxf(s[p], 0.f);
  __syncthreads();
  int c = j & 15;
#pragma unroll
  for (int pp=0;pp<2;++pp){
    int p = (j >> 4) + pp*4;
    float o = b2[c];
    for (int k=0;k<64;++k) o = fmaf(t[p][k], l2[k*16 + c], o);
    nodeout[(size_t)(n0+p)*16 + c] = o;
  }
}

// ---------------- per-graph readout: segmented reduce (batch is sorted) ----------------
__device__ __forceinline__ int lbound32(const int* __restrict__ a, int n, int v){
  int lo = 0, hi = n;
  while (lo < hi){ int mid = (lo+hi)>>1; if (a[mid] < v) lo = mid+1; else hi = mid; }
  return lo;
}
__device__ __forceinline__ int lbound64(const i64* __restrict__ a, int n, i64 v){
  int lo = 0, hi = n;
  while (lo < hi){ int mid = (lo+hi)>>1; if (a[mid] < v) lo = mid+1; else hi = mid; }
  return lo;
}
__global__ __launch_bounds__(256) void k_reduce(const float* __restrict__ nodeout,
    const int* __restrict__ batch, const int* __restrict__ flags, float* __restrict__ out){
  int g = blockIdx.x;
  int lo, hi;
  if (flags[1]){
    const i64* b64 = (const i64*)batch;
    lo = lbound64(b64, NN, (i64)g); hi = lbound64(b64, NN, (i64)g+1);
  } else {
    lo = lbound32(batch, NN, g); hi = lbound32(batch, NN, g+1);
  }
  int tid = threadIdx.x;
  int c = tid & 15, rr = tid >> 4;
  float s = 0.f;
  for (int r = lo + rr; r < hi; r += 16) s += nodeout[(size_t)r*16 + c];
  __shared__ float red[256];
  red[tid] = s; __syncthreads();
  for (int step = 128; step >= 16; step >>= 1){
    if (tid < step) red[tid] += red[tid + step];
    __syncthreads();
  }
  if (tid < 16) out[g*16 + tid] = red[tid];
}

// ---------------- launch ----------------
extern "C" void kernel_launch(void* const* d_in, const int* in_sizes, int n_in,
                              void* d_out, int out_size, void* d_ws, size_t ws_size,
                              hipStream_t stream){
  const float* x        = (const float*)d_in[0];
  const float* pos      = (const float*)d_in[1];
  const int*   edge     = (const int*)d_in[2];
  const int*   batch    = (const int*)d_in[3];
  const float* node_w1  = (const float*)d_in[4];
  const float* node_b1  = (const float*)d_in[5];
  const float* node_w2  = (const float*)d_in[6];
  const float* node_b2  = (const float*)d_in[7];
  const float* conv_w   = (const float*)d_in[8];
  const float* gru_wih  = (const float*)d_in[9];
  const float* gru_whh  = (const float*)d_in[10];
  const float* gru_bih  = (const float*)d_in[11];
  const float* gru_bhh  = (const float*)d_in[12];
  const float* lin1_w   = (const float*)d_in[13];
  const float* lin1_b   = (const float*)d_in[14];
  const float* lin2_w   = (const float*)d_in[15];
  const float* lin2_b   = (const float*)d_in[16];
  float* out = (float*)d_out;

  char* p = (char*)d_ws;
  int*   flags = (int*)p;   p += 256;
  float* h0    = (float*)p; p += (size_t)NN*128*4;
  float* h1    = (float*)p; p += (size_t)NN*128*4;   // ping-pong partner
  float* nodeout = (float*)p; p += (size_t)NN*16*4;
  int*   deg   = (int*)p;   p += (size_t)NN*4;
  int*   col   = (int*)p;   p += (size_t)NN*MAXDEG*4;
  float* wihT  = (float*)p; p += (size_t)3*49152*4;
  float* whhT  = (float*)p; p += (size_t)3*49152*4;
  float* WeffT = (float*)p; p += (size_t)9*49152*4;
  u16*   Bhi   = (u16*)p;   p += (size_t)9*512*256*2;
  u16*   Blo   = (u16*)p;   p += (size_t)9*512*256*2;

  k_detect<<<1, 512, 0, stream>>>(edge, batch, flags);
  hipMemsetAsync(deg, 0, (size_t)NN*4, stream);
  k_prep_wT<<<(147456 + 255)/256, 256, 0, stream>>>(gru_wih, gru_whh, wihT, whhT);
  k_weff<<<9*128, 384, 0, stream>>>(conv_w, wihT, WeffT);
  k_bsplit<<<9*512*256/256, 256, 0, stream>>>(WeffT, whhT, Bhi, Blo);
  k_fill_edges<<<NE/256, 256, 0, stream>>>(edge, flags, deg, col);
  k_enc_n<<<NN/8, 128, 0, stream>>>(x, pos, node_w1, node_b1, node_w2, node_b2, h0);

  float* hbuf[2] = { h0, h1 };
  for (int l = 0; l < 3; ++l){
    for (int i = 0; i < 3; ++i){
      int li = l*3 + i;
      k_fused<<<NN/32, 512, 0, stream>>>(deg, col, hbuf[li & 1], hbuf[(li + 1) & 1],
          Bhi + (size_t)li*131072, Blo + (size_t)li*131072,
          gru_bih + l*384, gru_bhh + l*384, (i==2) ? 1 : 0);
    }
  }
  k_head_n<<<NN/8, 64, 0, stream>>>(hbuf[1], lin1_w, lin1_b, lin2_w, lin2_b, nodeout);
  k_reduce<<<NG, 256, 0, stream>>>(nodeout, batch, flags, out);
}

// Round 11
// 1901.728 us; speedup vs baseline: 1.5072x; 1.0636x over previous
//
#include <hip/hip_runtime.h>

#define NN 100000
#define NE 1600000
#define NG 64
#define MAXDEG 64

typedef long long i64;
typedef unsigned short u16;
typedef unsigned int u32;
typedef __attribute__((ext_vector_type(8))) _Float16 f16x8;
typedef __attribute__((ext_vector_type(4))) _Float16 half4;
typedef __attribute__((ext_vector_type(4))) float f32x4;

__device__ __forceinline__ float sigm(float x){ return 1.f/(1.f+__expf(-x)); }
__device__ __forceinline__ float tanh_(float x){ return 2.f/(1.f+__expf(-2.f*x)) - 1.f; }
__device__ __forceinline__ f32x4 mfma16h(f16x8 a, f16x8 b, f32x4 c){
  return __builtin_amdgcn_mfma_f32_16x16x32_f16(a,b,c,0,0,0);
}
__device__ __forceinline__ u16 h2u(_Float16 h){ return *(const u16*)&h; }

// ---------------- int-width detection ----------------
__global__ __launch_bounds__(512) void k_detect(const int* __restrict__ ei,
    const int* __restrict__ batch, int* __restrict__ flags){
  int t = threadIdx.x;
  __shared__ int nz_e, nz_b;
  if (t == 0){ nz_e = 0; nz_b = 0; }
  __syncthreads();
  if (ei[2*t + 1] != 0) nz_e = 1;
  int k = NN/2 - 512 + t;
  if (batch[2*k + 1] != 0) nz_b = 1;
  __syncthreads();
  if (t == 0){ flags[0] = nz_e ? 0 : 1; flags[1] = nz_b ? 0 : 1; }
}

// ---------------- transposed GRU weights: wT[l][k][jc] = w[l][jc][k] ----------------
__global__ __launch_bounds__(256) void k_prep_wT(const float* __restrict__ wih,
    const float* __restrict__ whh, float* __restrict__ wihT, float* __restrict__ whhT){
  int idx = blockIdx.x*256 + threadIdx.x;            // 3*49152 = 147456
  if (idx >= 3*49152) return;
  int l = idx/49152, r = idx - l*49152, k = r/384, jc = r - k*384;
  wihT[idx] = wih[((size_t)l*384 + jc)*128 + k];
  whhT[idx] = whh[((size_t)l*384 + jc)*128 + k];
}

// ---------------- Weff fold: WeffT[li][k][jc] = sum_m cw[li][k][m] * wih[l][jc][m] ----------------
__global__ __launch_bounds__(384) void k_weff(const float* __restrict__ convw,
    const float* __restrict__ wihT, float* __restrict__ WeffT){
  int bid = blockIdx.x;               // 9*128
  int li = bid >> 7, k = bid & 127;
  int l = li / 3;
  int j = threadIdx.x;                // 0..383
  __shared__ float cwrow[128];
  if (j < 128) cwrow[j] = convw[((size_t)li*128 + k)*128 + j];
  __syncthreads();
  const float* wT = wihT + (size_t)l*49152;
  float acc = 0.f;
#pragma unroll 8
  for (int m = 0; m < 128; ++m)
    acc = fmaf(cwrow[m], wT[(size_t)m*384 + j], acc);
  WeffT[(size_t)li*49152 + (size_t)k*384 + j] = acc;
}

// ---------------- split fp16 B planes (GRU), MFMA-fragment-contiguous layout ----------------
__global__ __launch_bounds__(256) void k_bsplit(const float* __restrict__ WeffT,
    const float* __restrict__ whhT, u16* __restrict__ Bhi, u16* __restrict__ Blo){
  int idx = blockIdx.x*256 + threadIdx.x;   // 9*512*256 exact
  int li = idx >> 17;
  int r = idx & 131071;
  int col = r >> 8, k = r & 255;
  int l = li / 3;
  float v = 0.f;
  if (k < 128){
    if (col < 384) v = WeffT[(size_t)li*49152 + (size_t)k*384 + col];
  } else {
    int k2 = k - 128;
    if (col < 256)       v = whhT[(size_t)l*49152 + (size_t)k2*384 + col];
    else if (col >= 384) v = whhT[(size_t)l*49152 + (size_t)k2*384 + (col-128)];
  }
  _Float16 hi = (_Float16)v;
  _Float16 lo = (_Float16)(v - (float)hi);
  size_t widx = (size_t)li*131072 + ((((size_t)(k>>5))*512 + col)*4 + ((k>>3)&3))*8 + (k&7);
  Bhi[widx] = h2u(hi);
  Blo[widx] = h2u(lo);
}

// ---------------- padded adjacency by dst ----------------
__global__ __launch_bounds__(256) void k_fill_edges(const int* __restrict__ ei,
    const int* __restrict__ flags, int* __restrict__ deg, int* __restrict__ col){
  int e = blockIdx.x*256 + threadIdx.x;
  if (e >= NE) return;
  int s, d;
  if (flags[0]){
    const i64* e64 = (const i64*)ei;
    s = (int)e64[e]; d = (int)e64[NE + e];
  } else {
    s = ei[e]; d = ei[NE + e];
  }
  int slot = atomicAdd(&deg[d], 1);
  if (slot < MAXDEG) col[(size_t)d*MAXDEG + slot] = s;
}

// ---------------- encoder: fp32, 8 nodes/block (proven r3-r9) ----------------
__global__ __launch_bounds__(128) void k_enc_n(const float* __restrict__ x,
    const float* __restrict__ pos, const float* __restrict__ w1, const float* __restrict__ b1,
    const float* __restrict__ w2, const float* __restrict__ b2, float* __restrict__ h){
  int n0 = blockIdx.x * 8, j = threadIdx.x;
  __shared__ float xr[8][68];
  __shared__ float t1[8][128];
  for (int q = j; q < 8*67; q += 128){
    int p = q/67, kk = q - p*67;
    xr[p][kk] = (kk < 64) ? x[(size_t)(n0+p)*64 + kk] : pos[(size_t)(n0+p)*3 + (kk-64)];
  }
  __syncthreads();
  float s[8];
#pragma unroll
  for (int p=0;p<8;++p) s[p] = b1[j];
  for (int k=0;k<67;++k){
    float w = w1[k*128 + j];
#pragma unroll
    for (int p=0;p<8;++p) s[p] = fmaf(xr[p][k], w, s[p]);
  }
#pragma unroll
  for (int p=0;p<8;++p) t1[p][j] = fmaxf(s[p], 0.f);
  __syncthreads();
#pragma unroll
  for (int p=0;p<8;++p) s[p] = b2[j];
  for (int k=0;k<128;++k){
    float w = w2[k*128 + j];
#pragma unroll
    for (int p=0;p<8;++p) s[p] = fmaf(t1[p][k], w, s[p]);
  }
#pragma unroll
  for (int p=0;p<8;++p) h[(size_t)(n0+p)*128 + j] = s[p];
}

// ---------------- FUSED v4: gather (4-deep MLP) + split-fp16 3-pass MFMA GRU ----------------
__global__ __launch_bounds__(512, 8) void k_fused(const int* __restrict__ deg,
    const int* __restrict__ col, const float* __restrict__ hin, float* __restrict__ hout,
    const u16* __restrict__ Bhi, const u16* __restrict__ Blo,
    const float* __restrict__ bih, const float* __restrict__ bhh, int apply_relu){
  __shared__ u16 Ahi[32*256];
  __shared__ u16 Alo[32*256];
  const int tid = threadIdx.x, lane = tid & 63, w = tid >> 6;   // w in 0..7
  const int tile = blockIdx.x * 32;                             // 3125*32 = NN exact

  // stage h-half (cols 128..255): 32 rows x 32 float4 = 1024; 2 per thread
#pragma unroll
  for (int i = 0; i < 2; ++i){
    int f = i*512 + tid;
    int row = f >> 5, colq = f & 31;
    float4 v = *(const float4*)(hin + (size_t)(tile+row)*128 + colq*4);
    int colu = 128 + colq*4;
    int cs = (colu >> 3) ^ (row & 7);
    int idx = row*256 + cs*8 + (colu & 7);
    _Float16 h0=(_Float16)v.x, h1=(_Float16)v.y, h2=(_Float16)v.z, h3=(_Float16)v.w;
    _Float16 l0=(_Float16)(v.x-(float)h0), l1=(_Float16)(v.y-(float)h1),
             l2=(_Float16)(v.z-(float)h2), l3=(_Float16)(v.w-(float)h3);
    half4 hv = {h0,h1,h2,h3};
    half4 lv = {l0,l1,l2,l3};
    *(half4*)(Ahi + idx) = hv;
    *(half4*)(Alo + idx) = lv;
  }

  // gather ah-half (cols 0..127): 2 rows/wave; lane-half owns a row, 4-deep MLP
  const int half = lane >> 5, ln32 = lane & 31;
#pragma unroll
  for (int rr = 0; rr < 2; ++rr){
    int row = rr*16 + w*2 + half;
    int node = tile + row;
    int d = deg[node]; d = min(d, MAXDEG);
    int src1 = col[(size_t)node*MAXDEG + ln32];
    int src2 = col[(size_t)node*MAXDEG + 32 + ln32];
    float ax=0.f, ay=0.f, az=0.f, aw=0.f;
    int d1 = min(d, 32);
    int s = 0;
    for (; s + 3 < d1; s += 4){
      int a0 = __shfl(src1, half*32 + s, 64);
      int a1 = __shfl(src1, half*32 + s + 1, 64);
      int a2 = __shfl(src1, half*32 + s + 2, 64);
      int a3 = __shfl(src1, half*32 + s + 3, 64);
      float4 v0 = *(const float4*)(hin + (size_t)a0*128 + (ln32<<2));
      float4 v1 = *(const float4*)(hin + (size_t)a1*128 + (ln32<<2));
      float4 v2 = *(const float4*)(hin + (size_t)a2*128 + (ln32<<2));
      float4 v3 = *(const float4*)(hin + (size_t)a3*128 + (ln32<<2));
      ax += v0.x + v1.x + v2.x + v3.x;
      ay += v0.y + v1.y + v2.y + v3.y;
      az += v0.z + v1.z + v2.z + v3.z;
      aw += v0.w + v1.w + v2.w + v3.w;
    }
    for (; s < d1; ++s){
      int a0 = __shfl(src1, half*32 + s, 64);
      float4 v0 = *(const float4*)(hin + (size_t)a0*128 + (ln32<<2));
      ax += v0.x; ay += v0.y; az += v0.z; aw += v0.w;
    }
    int d2 = d - d1;
    s = 0;
    for (; s + 3 < d2; s += 4){
      int a0 = __shfl(src2, half*32 + s, 64);
      int a1 = __shfl(src2, half*32 + s + 1, 64);
      int a2 = __shfl(src2, half*32 + s + 2, 64);
      int a3 = __shfl(src2, half*32 + s + 3, 64);
      float4 v0 = *(const float4*)(hin + (size_t)a0*128 + (ln32<<2));
      float4 v1 = *(const float4*)(hin + (size_t)a1*128 + (ln32<<2));
      float4 v2 = *(const float4*)(hin + (size_t)a2*128 + (ln32<<2));
      float4 v3 = *(const float4*)(hin + (size_t)a3*128 + (ln32<<2));
      ax += v0.x + v1.x + v2.x + v3.x;
      ay += v0.y + v1.y + v2.y + v3.y;
      az += v0.z + v1.z + v2.z + v3.z;
      aw += v0.w + v1.w + v2.w + v3.w;
    }
    for (; s < d2; ++s){
      int a0 = __shfl(src2, half*32 + s, 64);
      float4 v0 = *(const float4*)(hin + (size_t)a0*128 + (ln32<<2));
      ax += v0.x; ay += v0.y; az += v0.z; aw += v0.w;
    }
    int colu = ln32 << 2;
    int cs = (colu >> 3) ^ (row & 7);
    int idx = row*256 + cs*8 + (colu & 7);
    _Float16 hx=(_Float16)ax, hy=(_Float16)ay, hz=(_Float16)az, hw=(_Float16)aw;
    _Float16 lx=(_Float16)(ax-(float)hx), ly=(_Float16)(ay-(float)hy),
             lz=(_Float16)(az-(float)hz), lw=(_Float16)(aw-(float)hw);
    half4 hv = {hx,hy,hz,hw};
    half4 lv = {lx,ly,lz,lw};
    *(half4*)(Ahi + idx) = hv;
    *(half4*)(Alo + idx) = lv;
  }
  __syncthreads();

  const f32x4 fz = {0.f,0.f,0.f,0.f};
  f32x4 acc[4][2];
#pragma unroll
  for (int g=0;g<4;++g)
#pragma unroll
    for (int R=0;R<2;++R) acc[g][R] = fz;

#pragma unroll
  for (int kk = 0; kk < 8; ++kk){
    f16x8 a_hi[2], a_lo[2];
#pragma unroll
    for (int R=0;R<2;++R){
      int arow = R*16 + (lane&15);
      int cs = (kk*4 + (lane>>4)) ^ (arow & 7);
      a_hi[R] = *(const f16x8*)(Ahi + arow*256 + cs*8);
      a_lo[R] = *(const f16x8*)(Alo + arow*256 + cs*8);
    }
#pragma unroll
    for (int g=0; g<4; ++g){
      if (g==2 && kk>=4) continue;   // inn: K[0,128) only
      if (g==3 && kk<4) continue;    // hn : K[128,256) only
      int colg = g*128 + w*16 + (lane&15);
      size_t boff = (((size_t)kk*512 + colg)*4 + (lane>>4))*8;
      f16x8 bh = *(const f16x8*)(Bhi + boff);
      f16x8 bl = *(const f16x8*)(Blo + boff);
#pragma unroll
      for (int R=0;R<2;++R){
        acc[g][R] = mfma16h(a_hi[R], bh, acc[g][R]);
        acc[g][R] = mfma16h(a_hi[R], bl, acc[g][R]);
        acc[g][R] = mfma16h(a_lo[R], bh, acc[g][R]);
      }
    }
  }

  // gate epilogue -> registers, then LDS-staged coalesced store
  float hn_reg[2][4];
  {
    int jj = w*16 + (lane&15);
    float br  = bih[jj]     + bhh[jj];
    float bz  = bih[128+jj] + bhh[128+jj];
    float bin = bih[256+jj];
    float bhn = bhh[256+jj];
#pragma unroll
    for (int R=0;R<2;++R)
#pragma unroll
      for (int v=0;v<4;++v){
        int r_ = R*16 + ((lane>>4)<<2) + v;
        float rg = sigm(acc[0][R][v] + br);
        float zg = sigm(acc[1][R][v] + bz);
        float hnv = acc[3][R][v] + bhn;
        float ng = tanh_(acc[2][R][v] + bin + rg*hnv);
        int colu = 128 + jj;
        int cs = (colu >> 3) ^ (r_ & 7);
        int lidx = r_*256 + cs*8 + (colu & 7);
        float hold = (float)(*(const _Float16*)(Ahi + lidx))
                   + (float)(*(const _Float16*)(Alo + lidx));
        float hnew = (1.f - zg)*ng + zg*hold;
        if (apply_relu) hnew = fmaxf(hnew, 0.f);
        hn_reg[R][v] = hnew;
      }
  }
  __syncthreads();
  float* fout = (float*)Ahi;               // reuse 16 KB as [32][128] f32
  {
    int jj = w*16 + (lane&15);
#pragma unroll
    for (int R=0;R<2;++R)
#pragma unroll
      for (int v=0;v<4;++v){
        int r_ = R*16 + ((lane>>4)<<2) + v;
        fout[r_*128 + jj] = hn_reg[R][v];
      }
  }
  __syncthreads();
#pragma unroll
  for (int i = 0; i < 2; ++i){
    int f = i*512 + tid;
    int row = f >> 5, colq = f & 31;
    float4 vv = *(const float4*)(fout + row*128 + colq*4);
    *(float4*)(hout + (size_t)(tile+row)*128 + colq*4) = vv;
  }
}

// ---------------- head: fp32, 8 nodes/block (unchanged) ----------------
__global__ __launch_bounds__(64) void k_head_n(const float* __restrict__ h,
    const float* __restrict__ l1, const float* __restrict__ b1,
    const float* __restrict__ l2, const float* __restrict__ b2, float* __restrict__ nodeout){
  int n0 = blockIdx.x * 8, j = threadIdx.x;
  __shared__ float hrow[8][128], t[8][64];
  for (int q = j; q < 1024; q += 64){
    int p = q >> 7, k = q & 127;
    hrow[p][k] = h[(size_t)(n0+p)*128 + k];
  }
  __syncthreads();
  float s[8];
#pragma unroll
  for (int p=0;p<8;++p) s[p] = b1[j];
  for (int k=0;k<128;++k){
    float w = l1[k*64 + j];
#pragma unroll
    for (int p=0;p<8;++p) s[p] = fmaf(hrow[p][k], w, s[p]);
  }
#pragma unroll
  for (int p=0;p<8;++p) t[p][j] = fmaxf(s[p], 0.f);
  __syncthreads();
  int c = j & 15;
#pragma unroll
  for (int pp=0;pp<2;++pp){
    int p = (j >> 4) + pp*4;
    float o = b2[c];
    for (int k=0;k<64;++k) o = fmaf(t[p][k], l2[k*16 + c], o);
    nodeout[(size_t)(n0+p)*16 + c] = o;
  }
}

// ---------------- per-graph readout: segmented reduce (batch is sorted) ----------------
__device__ __forceinline__ int lbound32(const int* __restrict__ a, int n, int v){
  int lo = 0, hi = n;
  while (lo < hi){ int mid = (lo+hi)>>1; if (a[mid] < v) lo = mid+1; else hi = mid; }
  return lo;
}
__device__ __forceinline__ int lbound64(const i64* __restrict__ a, int n, i64 v){
  int lo = 0, hi = n;
  while (lo < hi){ int mid = (lo+hi)>>1; if (a[mid] < v) lo = mid+1; else hi = mid; }
  return lo;
}
__global__ __launch_bounds__(256) void k_reduce(const float* __restrict__ nodeout,
    const int* __restrict__ batch, const int* __restrict__ flags, float* __restrict__ out){
  int g = blockIdx.x;
  int lo, hi;
  if (flags[1]){
    const i64* b64 = (const i64*)batch;
    lo = lbound64(b64, NN, (i64)g); hi = lbound64(b64, NN, (i64)g+1);
  } else {
    lo = lbound32(batch, NN, g); hi = lbound32(batch, NN, g+1);
  }
  int tid = threadIdx.x;
  int c = tid & 15, rr = tid >> 4;
  float s = 0.f;
  for (int r = lo + rr; r < hi; r += 16) s += nodeout[(size_t)r*16 + c];
  __shared__ float red[256];
  red[tid] = s; __syncthreads();
  for (int step = 128; step >= 16; step >>= 1){
    if (tid < step) red[tid] += red[tid + step];
    __syncthreads();
  }
  if (tid < 16) out[g*16 + tid] = red[tid];
}

// ---------------- launch ----------------
extern "C" void kernel_launch(void* const* d_in, const int* in_sizes, int n_in,
                              void* d_out, int out_size, void* d_ws, size_t ws_size,
                              hipStream_t stream){
  const float* x        = (const float*)d_in[0];
  const float* pos      = (const float*)d_in[1];
  const int*   edge     = (const int*)d_in[2];
  const int*   batch    = (const int*)d_in[3];
  const float* node_w1  = (const float*)d_in[4];
  const float* node_b1  = (const float*)d_in[5];
  const float* node_w2  = (const float*)d_in[6];
  const float* node_b2  = (const float*)d_in[7];
  const float* conv_w   = (const float*)d_in[8];
  const float* gru_wih  = (const float*)d_in[9];
  const float* gru_whh  = (const float*)d_in[10];
  const float* gru_bih  = (const float*)d_in[11];
  const float* gru_bhh  = (const float*)d_in[12];
  const float* lin1_w   = (const float*)d_in[13];
  const float* lin1_b   = (const float*)d_in[14];
  const float* lin2_w   = (const float*)d_in[15];
  const float* lin2_b   = (const float*)d_in[16];
  float* out = (float*)d_out;

  char* p = (char*)d_ws;
  int*   flags = (int*)p;   p += 256;
  float* h0    = (float*)p; p += (size_t)NN*128*4;
  float* h1    = (float*)p; p += (size_t)NN*128*4;   // ping-pong partner
  float* nodeout = (float*)p; p += (size_t)NN*16*4;
  int*   deg   = (int*)p;   p += (size_t)NN*4;
  int*   col   = (int*)p;   p += (size_t)NN*MAXDEG*4;
  float* wihT  = (float*)p; p += (size_t)3*49152*4;
  float* whhT  = (float*)p; p += (size_t)3*49152*4;
  float* WeffT = (float*)p; p += (size_t)9*49152*4;
  u16*   Bhi   = (u16*)p;   p += (size_t)9*512*256*2;
  u16*   Blo   = (u16*)p;   p += (size_t)9*512*256*2;

  k_detect<<<1, 512, 0, stream>>>(edge, batch, flags);
  hipMemsetAsync(deg, 0, (size_t)NN*4, stream);
  k_prep_wT<<<(147456 + 255)/256, 256, 0, stream>>>(gru_wih, gru_whh, wihT, whhT);
  k_weff<<<9*128, 384, 0, stream>>>(conv_w, wihT, WeffT);
  k_bsplit<<<9*512*256/256, 256, 0, stream>>>(WeffT, whhT, Bhi, Blo);
  k_fill_edges<<<NE/256, 256, 0, stream>>>(edge, flags, deg, col);
  k_enc_n<<<NN/8, 128, 0, stream>>>(x, pos, node_w1, node_b1, node_w2, node_b2, h0);

  float* hbuf[2] = { h0, h1 };
  for (int l = 0; l < 3; ++l){
    for (int i = 0; i < 3; ++i){
      int li = l*3 + i;
      k_fused<<<NN/32, 512, 0, stream>>>(deg, col, hbuf[li & 1], hbuf[(li + 1) & 1],
          Bhi + (size_t)li*131072, Blo + (size_t)li*131072,
          gru_bih + l*384, gru_bhh + l*384, (i==2) ? 1 : 0);
    }
  }
  k_head_n<<<NN/8, 64, 0, stream>>>(hbuf[1], lin1_w, lin1_b, lin2_w, lin2_b, nodeout);
  k_reduce<<<NG, 256, 0, stream>>>(nodeout, batch, flags, out);
}

// Round 12
// 1883.008 us; speedup vs baseline: 1.5222x; 1.0099x over previous
//
#include <hip/hip_runtime.h>

#define NN 100000
#define NE 1600000
#define NG 64
#define MAXDEG 64

typedef long long i64;
typedef unsigned short u16;
typedef unsigned int u32;
typedef __attribute__((ext_vector_type(8))) _Float16 f16x8;
typedef __attribute__((ext_vector_type(4))) _Float16 half4;
typedef __attribute__((ext_vector_type(4))) float f32x4;

__device__ __forceinline__ float sigm(float x){ return 1.f/(1.f+__expf(-x)); }
__device__ __forceinline__ float tanh_(float x){ return 2.f/(1.f+__expf(-2.f*x)) - 1.f; }
__device__ __forceinline__ f32x4 mfma16h(f16x8 a, f16x8 b, f32x4 c){
  return __builtin_amdgcn_mfma_f32_16x16x32_f16(a,b,c,0,0,0);
}
__device__ __forceinline__ u16 h2u(_Float16 h){ return *(const u16*)&h; }

// ---------------- int-width detection ----------------
__global__ __launch_bounds__(512) void k_detect(const int* __restrict__ ei,
    const int* __restrict__ batch, int* __restrict__ flags){
  int t = threadIdx.x;
  __shared__ int nz_e, nz_b;
  if (t == 0){ nz_e = 0; nz_b = 0; }
  __syncthreads();
  if (ei[2*t + 1] != 0) nz_e = 1;
  int k = NN/2 - 512 + t;
  if (batch[2*k + 1] != 0) nz_b = 1;
  __syncthreads();
  if (t == 0){ flags[0] = nz_e ? 0 : 1; flags[1] = nz_b ? 0 : 1; }
}

// ---------------- transposed GRU weights: wT[l][k][jc] = w[l][jc][k] ----------------
__global__ __launch_bounds__(256) void k_prep_wT(const float* __restrict__ wih,
    const float* __restrict__ whh, float* __restrict__ wihT, float* __restrict__ whhT){
  int idx = blockIdx.x*256 + threadIdx.x;            // 3*49152 = 147456
  if (idx >= 3*49152) return;
  int l = idx/49152, r = idx - l*49152, k = r/384, jc = r - k*384;
  wihT[idx] = wih[((size_t)l*384 + jc)*128 + k];
  whhT[idx] = whh[((size_t)l*384 + jc)*128 + k];
}

// ---------------- Weff fold: WeffT[li][k][jc] = sum_m cw[li][k][m] * wih[l][jc][m] ----------------
__global__ __launch_bounds__(384) void k_weff(const float* __restrict__ convw,
    const float* __restrict__ wihT, float* __restrict__ WeffT){
  int bid = blockIdx.x;               // 9*128
  int li = bid >> 7, k = bid & 127;
  int l = li / 3;
  int j = threadIdx.x;                // 0..383
  __shared__ float cwrow[128];
  if (j < 128) cwrow[j] = convw[((size_t)li*128 + k)*128 + j];
  __syncthreads();
  const float* wT = wihT + (size_t)l*49152;
  float acc = 0.f;
#pragma unroll 8
  for (int m = 0; m < 128; ++m)
    acc = fmaf(cwrow[m], wT[(size_t)m*384 + j], acc);
  WeffT[(size_t)li*49152 + (size_t)k*384 + j] = acc;
}

// ---------------- split fp16 B planes (GRU), MFMA-fragment-contiguous layout ----------------
__global__ __launch_bounds__(256) void k_bsplit(const float* __restrict__ WeffT,
    const float* __restrict__ whhT, u16* __restrict__ Bhi, u16* __restrict__ Blo){
  int idx = blockIdx.x*256 + threadIdx.x;   // 9*512*256 exact
  int li = idx >> 17;
  int r = idx & 131071;
  int col = r >> 8, k = r & 255;
  int l = li / 3;
  float v = 0.f;
  if (k < 128){
    if (col < 384) v = WeffT[(size_t)li*49152 + (size_t)k*384 + col];
  } else {
    int k2 = k - 128;
    if (col < 256)       v = whhT[(size_t)l*49152 + (size_t)k2*384 + col];
    else if (col >= 384) v = whhT[(size_t)l*49152 + (size_t)k2*384 + (col-128)];
  }
  _Float16 hi = (_Float16)v;
  _Float16 lo = (_Float16)(v - (float)hi);
  size_t widx = (size_t)li*131072 + ((((size_t)(k>>5))*512 + col)*4 + ((k>>3)&3))*8 + (k&7);
  Bhi[widx] = h2u(hi);
  Blo[widx] = h2u(lo);
}

// ---------------- split fp16 B planes (encoder W1 67->96pad, W2 128) ----------------
__global__ __launch_bounds__(256) void k_bsplit_enc(const float* __restrict__ w1,
    const float* __restrict__ w2, u16* __restrict__ B1hi, u16* __restrict__ B1lo,
    u16* __restrict__ B2hi, u16* __restrict__ B2lo){
  int idx = blockIdx.x*256 + threadIdx.x;    // 12288 + 16384 = 28672 exact
  if (idx < 12288){
    int j = idx / 96, k = idx - j*96;
    float v = (k < 67) ? w1[k*128 + j] : 0.f;
    _Float16 hi = (_Float16)v;
    _Float16 lo = (_Float16)(v - (float)hi);
    size_t widx = ((((size_t)(k>>5))*128 + j)*4 + ((k>>3)&3))*8 + (k&7);
    B1hi[widx] = h2u(hi);
    B1lo[widx] = h2u(lo);
  } else {
    int r = idx - 12288;
    int j = r >> 7, k = r & 127;
    float v = w2[k*128 + j];
    _Float16 hi = (_Float16)v;
    _Float16 lo = (_Float16)(v - (float)hi);
    size_t widx = ((((size_t)(k>>5))*128 + j)*4 + ((k>>3)&3))*8 + (k&7);
    B2hi[widx] = h2u(hi);
    B2lo[widx] = h2u(lo);
  }
}

// ---------------- padded adjacency by dst ----------------
__global__ __launch_bounds__(256) void k_fill_edges(const int* __restrict__ ei,
    const int* __restrict__ flags, int* __restrict__ deg, int* __restrict__ col){
  int e = blockIdx.x*256 + threadIdx.x;
  if (e >= NE) return;
  int s, d;
  if (flags[0]){
    const i64* e64 = (const i64*)ei;
    s = (int)e64[e]; d = (int)e64[NE + e];
  } else {
    s = ei[e]; d = ei[NE + e];
  }
  int slot = atomicAdd(&deg[d], 1);
  if (slot < MAXDEG) col[(size_t)d*MAXDEG + slot] = s;
}

// ---------------- encoder: split-fp16 MFMA, 32-row tile, 8 waves, ROBUST zero-fill ----------------
// h = relu([x|pos]@w1+b1)@w2+b2. K1=96 (67 padded), K2=128.
__global__ __launch_bounds__(512, 8) void k_enc_mfma(const float* __restrict__ x,
    const float* __restrict__ pos,
    const u16* __restrict__ B1hi, const u16* __restrict__ B1lo,
    const u16* __restrict__ B2hi, const u16* __restrict__ B2lo,
    const float* __restrict__ b1, const float* __restrict__ b2, float* __restrict__ h){
  __shared__ u16 lds[4*32*128];                 // 32 KB
  u16* Ahi = lds;            u16* Alo = lds + 4096;
  u16* Thi = lds + 8192;     u16* Tlo = lds + 12288;
  const int tid = threadIdx.x, lane = tid & 63, w = tid >> 6;
  const int tile = blockIdx.x * 32;             // NN/32 exact

  // phase 0: zero-fill ENTIRE Ahi/Alo planes (exact coverage: 512 thr x 8 u16/plane)
  {
    int o = tid * 8;
    half4 z = {0,0,0,0};
    *(half4*)(Ahi + o) = z;  *(half4*)(Ahi + o + 4) = z;
    *(half4*)(Alo + o) = z;  *(half4*)(Alo + o + 4) = z;
  }
  __syncthreads();

  // phase 1: stage x (cols 0..63, full chunks) + pos (cols 64..67 as one half4, 67=0)
  {
    int row = tid >> 4, colq = tid & 15;
    float4 v = *(const float4*)(x + (size_t)(tile+row)*64 + colq*4);
    int colu = colq*4;
    int cs = (colu >> 3) ^ (row & 7);
    int idx = row*128 + cs*8 + (colu & 7);
    _Float16 h0=(_Float16)v.x, h1=(_Float16)v.y, h2=(_Float16)v.z, h3=(_Float16)v.w;
    _Float16 l0=(_Float16)(v.x-(float)h0), l1=(_Float16)(v.y-(float)h1),
             l2=(_Float16)(v.z-(float)h2), l3=(_Float16)(v.w-(float)h3);
    half4 hv = {h0,h1,h2,h3};
    half4 lv = {l0,l1,l2,l3};
    *(half4*)(Ahi + idx) = hv;
    *(half4*)(Alo + idx) = lv;
  }
  if (tid < 32){
    int row = tid;
    int n = tile + row;
    float p0 = pos[(size_t)n*3], p1 = pos[(size_t)n*3+1], p2 = pos[(size_t)n*3+2];
    _Float16 h0=(_Float16)p0, h1=(_Float16)p1, h2=(_Float16)p2;
    _Float16 l0=(_Float16)(p0-(float)h0), l1=(_Float16)(p1-(float)h1), l2=(_Float16)(p2-(float)h2);
    int cs = 8 ^ (row & 7);                    // colu=64 -> chunk 8, e4=0
    int idx = row*128 + cs*8;
    half4 hv = {h0,h1,h2,(_Float16)0.f};
    half4 lv = {l0,l1,l2,(_Float16)0.f};
    *(half4*)(Ahi + idx) = hv;
    *(half4*)(Alo + idx) = lv;
  }
  __syncthreads();

  const f32x4 fz = {0.f,0.f,0.f,0.f};
  // layer 1: K=96 (kk 0..2)
  f32x4 acc1[2] = {fz, fz};
#pragma unroll
  for (int kk = 0; kk < 3; ++kk){
    f16x8 a_hi[2], a_lo[2];
#pragma unroll
    for (int R=0;R<2;++R){
      int arow = R*16 + (lane&15);
      int cs = (kk*4 + (lane>>4)) ^ (arow & 7);
      a_hi[R] = *(const f16x8*)(Ahi + arow*128 + cs*8);
      a_lo[R] = *(const f16x8*)(Alo + arow*128 + cs*8);
    }
    int colg = w*16 + (lane&15);
    size_t boff = (((size_t)kk*128 + colg)*4 + (lane>>4))*8;
    f16x8 bh = *(const f16x8*)(B1hi + boff);
    f16x8 bl = *(const f16x8*)(B1lo + boff);
#pragma unroll
    for (int R=0;R<2;++R){
      acc1[R] = mfma16h(a_hi[R], bh, acc1[R]);
      acc1[R] = mfma16h(a_hi[R], bl, acc1[R]);
      acc1[R] = mfma16h(a_lo[R], bh, acc1[R]);
    }
  }
  // relu + bias -> T (split fp16, swizzled)
  {
    int jj = w*16 + (lane&15);
    float bias1 = b1[jj];
#pragma unroll
    for (int R=0;R<2;++R)
#pragma unroll
      for (int v=0;v<4;++v){
        int r_ = R*16 + ((lane>>4)<<2) + v;
        float t = fmaxf(acc1[R][v] + bias1, 0.f);
        _Float16 hi = (_Float16)t;
        _Float16 lo = (_Float16)(t - (float)hi);
        int cs = (jj >> 3) ^ (r_ & 7);
        int idx = r_*128 + cs*8 + (jj & 7);
        Thi[idx] = h2u(hi);
        Tlo[idx] = h2u(lo);
      }
  }
  __syncthreads();

  // layer 2: K=128 (kk 0..3)
  f32x4 acc2[2] = {fz, fz};
#pragma unroll
  for (int kk = 0; kk < 4; ++kk){
    f16x8 a_hi[2], a_lo[2];
#pragma unroll
    for (int R=0;R<2;++R){
      int arow = R*16 + (lane&15);
      int cs = (kk*4 + (lane>>4)) ^ (arow & 7);
      a_hi[R] = *(const f16x8*)(Thi + arow*128 + cs*8);
      a_lo[R] = *(const f16x8*)(Tlo + arow*128 + cs*8);
    }
    int colg = w*16 + (lane&15);
    size_t boff = (((size_t)kk*128 + colg)*4 + (lane>>4))*8;
    f16x8 bh = *(const f16x8*)(B2hi + boff);
    f16x8 bl = *(const f16x8*)(B2lo + boff);
#pragma unroll
    for (int R=0;R<2;++R){
      acc2[R] = mfma16h(a_hi[R], bh, acc2[R]);
      acc2[R] = mfma16h(a_hi[R], bl, acc2[R]);
      acc2[R] = mfma16h(a_lo[R], bh, acc2[R]);
    }
  }
  // bias -> fout (fp32, reuse A region; A no longer read) -> coalesced store
  float* fout = (float*)lds;
  {
    int jj = w*16 + (lane&15);
    float bias2 = b2[jj];
#pragma unroll
    for (int R=0;R<2;++R)
#pragma unroll
      for (int v=0;v<4;++v){
        int r_ = R*16 + ((lane>>4)<<2) + v;
        fout[r_*128 + jj] = acc2[R][v] + bias2;
      }
  }
  __syncthreads();
#pragma unroll
  for (int i = 0; i < 2; ++i){
    int f = i*512 + tid;
    int row = f >> 5, colq = f & 31;
    float4 vv = *(const float4*)(fout + row*128 + colq*4);
    *(float4*)(h + (size_t)(tile+row)*128 + colq*4) = vv;
  }
}

// ---------------- FUSED v5: gather (8-deep MLP) + split-fp16 3-pass MFMA GRU ----------------
__global__ __launch_bounds__(512, 8) void k_fused(const int* __restrict__ deg,
    const int* __restrict__ col, const float* __restrict__ hin, float* __restrict__ hout,
    const u16* __restrict__ Bhi, const u16* __restrict__ Blo,
    const float* __restrict__ bih, const float* __restrict__ bhh, int apply_relu){
  __shared__ u16 Ahi[32*256];
  __shared__ u16 Alo[32*256];
  const int tid = threadIdx.x, lane = tid & 63, w = tid >> 6;   // w in 0..7
  const int tile = blockIdx.x * 32;                             // 3125*32 = NN exact

  // stage h-half (cols 128..255): 32 rows x 32 float4 = 1024; 2 per thread
#pragma unroll
  for (int i = 0; i < 2; ++i){
    int f = i*512 + tid;
    int row = f >> 5, colq = f & 31;
    float4 v = *(const float4*)(hin + (size_t)(tile+row)*128 + colq*4);
    int colu = 128 + colq*4;
    int cs = (colu >> 3) ^ (row & 7);
    int idx = row*256 + cs*8 + (colu & 7);
    _Float16 h0=(_Float16)v.x, h1=(_Float16)v.y, h2=(_Float16)v.z, h3=(_Float16)v.w;
    _Float16 l0=(_Float16)(v.x-(float)h0), l1=(_Float16)(v.y-(float)h1),
             l2=(_Float16)(v.z-(float)h2), l3=(_Float16)(v.w-(float)h3);
    half4 hv = {h0,h1,h2,h3};
    half4 lv = {l0,l1,l2,l3};
    *(half4*)(Ahi + idx) = hv;
    *(half4*)(Alo + idx) = lv;
  }

  // gather ah-half (cols 0..127): 2 rows/wave; lane-half owns a row; 8-deep MLP
  const int half = lane >> 5, ln32 = lane & 31;
#pragma unroll
  for (int rr = 0; rr < 2; ++rr){
    int row = rr*16 + w*2 + half;
    int node = tile + row;
    int d = deg[node]; d = min(d, MAXDEG);
    int src1 = col[(size_t)node*MAXDEG + ln32];
    int src2 = col[(size_t)node*MAXDEG + 32 + ln32];
    float ax=0.f, ay=0.f, az=0.f, aw=0.f;
    int d1 = min(d, 32);
    int s = 0;
    for (; s + 7 < d1; s += 8){
      int a0 = __shfl(src1, half*32 + s,     64);
      int a1 = __shfl(src1, half*32 + s + 1, 64);
      int a2 = __shfl(src1, half*32 + s + 2, 64);
      int a3 = __shfl(src1, half*32 + s + 3, 64);
      int a4 = __shfl(src1, half*32 + s + 4, 64);
      int a5 = __shfl(src1, half*32 + s + 5, 64);
      int a6 = __shfl(src1, half*32 + s + 6, 64);
      int a7 = __shfl(src1, half*32 + s + 7, 64);
      float4 v0 = *(const float4*)(hin + (size_t)a0*128 + (ln32<<2));
      float4 v1 = *(const float4*)(hin + (size_t)a1*128 + (ln32<<2));
      float4 v2 = *(const float4*)(hin + (size_t)a2*128 + (ln32<<2));
      float4 v3 = *(const float4*)(hin + (size_t)a3*128 + (ln32<<2));
      float4 v4 = *(const float4*)(hin + (size_t)a4*128 + (ln32<<2));
      float4 v5 = *(const float4*)(hin + (size_t)a5*128 + (ln32<<2));
      float4 v6 = *(const float4*)(hin + (size_t)a6*128 + (ln32<<2));
      float4 v7 = *(const float4*)(hin + (size_t)a7*128 + (ln32<<2));
      ax += v0.x + v1.x + v2.x + v3.x + v4.x + v5.x + v6.x + v7.x;
      ay += v0.y + v1.y + v2.y + v3.y + v4.y + v5.y + v6.y + v7.y;
      az += v0.z + v1.z + v2.z + v3.z + v4.z + v5.z + v6.z + v7.z;
      aw += v0.w + v1.w + v2.w + v3.w + v4.w + v5.w + v6.w + v7.w;
    }
    for (; s < d1; ++s){
      int a0 = __shfl(src1, half*32 + s, 64);
      float4 v0 = *(const float4*)(hin + (size_t)a0*128 + (ln32<<2));
      ax += v0.x; ay += v0.y; az += v0.z; aw += v0.w;
    }
    int d2 = d - d1;
    s = 0;
    for (; s + 3 < d2; s += 4){
      int a0 = __shfl(src2, half*32 + s,     64);
      int a1 = __shfl(src2, half*32 + s + 1, 64);
      int a2 = __shfl(src2, half*32 + s + 2, 64);
      int a3 = __shfl(src2, half*32 + s + 3, 64);
      float4 v0 = *(const float4*)(hin + (size_t)a0*128 + (ln32<<2));
      float4 v1 = *(const float4*)(hin + (size_t)a1*128 + (ln32<<2));
      float4 v2 = *(const float4*)(hin + (size_t)a2*128 + (ln32<<2));
      float4 v3 = *(const float4*)(hin + (size_t)a3*128 + (ln32<<2));
      ax += v0.x + v1.x + v2.x + v3.x;
      ay += v0.y + v1.y + v2.y + v3.y;
      az += v0.z + v1.z + v2.z + v3.z;
      aw += v0.w + v1.w + v2.w + v3.w;
    }
    for (; s < d2; ++s){
      int a0 = __shfl(src2, half*32 + s, 64);
      float4 v0 = *(const float4*)(hin + (size_t)a0*128 + (ln32<<2));
      ax += v0.x; ay += v0.y; az += v0.z; aw += v0.w;
    }
    int colu = ln32 << 2;
    int cs = (colu >> 3) ^ (row & 7);
    int idx = row*256 + cs*8 + (colu & 7);
    _Float16 hx=(_Float16)ax, hy=(_Float16)ay, hz=(_Float16)az, hw=(_Float16)aw;
    _Float16 lx=(_Float16)(ax-(float)hx), ly=(_Float16)(ay-(float)hy),
             lz=(_Float16)(az-(float)hz), lw=(_Float16)(aw-(float)hw);
    half4 hv = {hx,hy,hz,hw};
    half4 lv = {lx,ly,lz,lw};
    *(half4*)(Ahi + idx) = hv;
    *(half4*)(Alo + idx) = lv;
  }
  __syncthreads();

  const f32x4 fz = {0.f,0.f,0.f,0.f};
  f32x4 acc[4][2];
#pragma unroll
  for (int g=0;g<4;++g)
#pragma unroll
    for (int R=0;R<2;++R) acc[g][R] = fz;

#pragma unroll
  for (int kk = 0; kk < 8; ++kk){
    f16x8 a_hi[2], a_lo[2];
#pragma unroll
    for (int R=0;R<2;++R){
      int arow = R*16 + (lane&15);
      int cs = (kk*4 + (lane>>4)) ^ (arow & 7);
      a_hi[R] = *(const f16x8*)(Ahi + arow*256 + cs*8);
      a_lo[R] = *(const f16x8*)(Alo + arow*256 + cs*8);
    }
#pragma unroll
    for (int g=0; g<4; ++g){
      if (g==2 && kk>=4) continue;   // inn: K[0,128) only
      if (g==3 && kk<4) continue;    // hn : K[128,256) only
      int colg = g*128 + w*16 + (lane&15);
      size_t boff = (((size_t)kk*512 + colg)*4 + (lane>>4))*8;
      f16x8 bh = *(const f16x8*)(Bhi + boff);
      f16x8 bl = *(const f16x8*)(Blo + boff);
#pragma unroll
      for (int R=0;R<2;++R){
        acc[g][R] = mfma16h(a_hi[R], bh, acc[g][R]);
        acc[g][R] = mfma16h(a_hi[R], bl, acc[g][R]);
        acc[g][R] = mfma16h(a_lo[R], bh, acc[g][R]);
      }
    }
  }

  // gate epilogue -> registers, then LDS-staged coalesced store
  float hn_reg[2][4];
  {
    int jj = w*16 + (lane&15);
    float br  = bih[jj]     + bhh[jj];
    float bz  = bih[128+jj] + bhh[128+jj];
    float bin = bih[256+jj];
    float bhn = bhh[256+jj];
#pragma unroll
    for (int R=0;R<2;++R)
#pragma unroll
      for (int v=0;v<4;++v){
        int r_ = R*16 + ((lane>>4)<<2) + v;
        float rg = sigm(acc[0][R][v] + br);
        float zg = sigm(acc[1][R][v] + bz);
        float hnv = acc[3][R][v] + bhn;
        float ng = tanh_(acc[2][R][v] + bin + rg*hnv);
        int colu = 128 + jj;
        int cs = (colu >> 3) ^ (r_ & 7);
        int lidx = r_*256 + cs*8 + (colu & 7);
        float hold = (float)(*(const _Float16*)(Ahi + lidx))
                   + (float)(*(const _Float16*)(Alo + lidx));
        float hnew = (1.f - zg)*ng + zg*hold;
        if (apply_relu) hnew = fmaxf(hnew, 0.f);
        hn_reg[R][v] = hnew;
      }
  }
  __syncthreads();
  float* fout = (float*)Ahi;               // reuse 16 KB as [32][128] f32
  {
    int jj = w*16 + (lane&15);
#pragma unroll
    for (int R=0;R<2;++R)
#pragma unroll
      for (int v=0;v<4;++v){
        int r_ = R*16 + ((lane>>4)<<2) + v;
        fout[r_*128 + jj] = hn_reg[R][v];
      }
  }
  __syncthreads();
#pragma unroll
  for (int i = 0; i < 2; ++i){
    int f = i*512 + tid;
    int row = f >> 5, colq = f & 31;
    float4 vv = *(const float4*)(fout + row*128 + colq*4);
    *(float4*)(hout + (size_t)(tile+row)*128 + colq*4) = vv;
  }
}

// ---------------- head: fp32, 8 nodes/block (unchanged) ----------------
__global__ __launch_bounds__(64) void k_head_n(const float* __restrict__ h,
    const float* __restrict__ l1, const float* __restrict__ b1,
    const float* __restrict__ l2, const float* __restrict__ b2, float* __restrict__ nodeout){
  int n0 = blockIdx.x * 8, j = threadIdx.x;
  __shared__ float hrow[8][128], t[8][64];
  for (int q = j; q < 1024; q += 64){
    int p = q >> 7, k = q & 127;
    hrow[p][k] = h[(size_t)(n0+p)*128 + k];
  }
  __syncthreads();
  float s[8];
#pragma unroll
  for (int p=0;p<8;++p) s[p] = b1[j];
  for (int k=0;k<128;++k){
    float w = l1[k*64 + j];
#pragma unroll
    for (int p=0;p<8;++p) s[p] = fmaf(hrow[p][k], w, s[p]);
  }
#pragma unroll
  for (int p=0;p<8;++p) t[p][j] = fmaxf(s[p], 0.f);
  __syncthreads();
  int c = j & 15;
#pragma unroll
  for (int pp=0;pp<2;++pp){
    int p = (j >> 4) + pp*4;
    float o = b2[c];
    for (int k=0;k<64;++k) o = fmaf(t[p][k], l2[k*16 + c], o);
    nodeout[(size_t)(n0+p)*16 + c] = o;
  }
}

// ---------------- per-graph readout: segmented reduce (batch is sorted) ----------------
__device__ __forceinline__ int lbound32(const int* __restrict__ a, int n, int v){
  int lo = 0, hi = n;
  while (lo < hi){ int mid = (lo+hi)>>1; if (a[mid] < v) lo = mid+1; else hi = mid; }
  return lo;
}
__device__ __forceinline__ int lbound64(const i64* __restrict__ a, int n, i64 v){
  int lo = 0, hi = n;
  while (lo < hi){ int mid = (lo+hi)>>1; if (a[mid] < v) lo = mid+1; else hi = mid; }
  return lo;
}
__global__ __launch_bounds__(256) void k_reduce(const float* __restrict__ nodeout,
    const int* __restrict__ batch, const int* __restrict__ flags, float* __restrict__ out){
  int g = blockIdx.x;
  int lo, hi;
  if (flags[1]){
    const i64* b64 = (const i64*)batch;
    lo = lbound64(b64, NN, (i64)g); hi = lbound64(b64, NN, (i64)g+1);
  } else {
    lo = lbound32(batch, NN, g); hi = lbound32(batch, NN, g+1);
  }
  int tid = threadIdx.x;
  int c = tid & 15, rr = tid >> 4;
  float s = 0.f;
  for (int r = lo + rr; r < hi; r += 16) s += nodeout[(size_t)r*16 + c];
  __shared__ float red[256];
  red[tid] = s; __syncthreads();
  for (int step = 128; step >= 16; step >>= 1){
    if (tid < step) red[tid] += red[tid + step];
    __syncthreads();
  }
  if (tid < 16) out[g*16 + tid] = red[tid];
}

// ---------------- launch ----------------
extern "C" void kernel_launch(void* const* d_in, const int* in_sizes, int n_in,
                              void* d_out, int out_size, void* d_ws, size_t ws_size,
                              hipStream_t stream){
  const float* x        = (const float*)d_in[0];
  const float* pos      = (const float*)d_in[1];
  const int*   edge     = (const int*)d_in[2];
  const int*   batch    = (const int*)d_in[3];
  const float* node_w1  = (const float*)d_in[4];
  const float* node_b1  = (const float*)d_in[5];
  const float* node_w2  = (const float*)d_in[6];
  const float* node_b2  = (const float*)d_in[7];
  const float* conv_w   = (const float*)d_in[8];
  const float* gru_wih  = (const float*)d_in[9];
  const float* gru_whh  = (const float*)d_in[10];
  const float* gru_bih  = (const float*)d_in[11];
  const float* gru_bhh  = (const float*)d_in[12];
  const float* lin1_w   = (const float*)d_in[13];
  const float* lin1_b   = (const float*)d_in[14];
  const float* lin2_w   = (const float*)d_in[15];
  const float* lin2_b   = (const float*)d_in[16];
  float* out = (float*)d_out;

  char* p = (char*)d_ws;
  int*   flags = (int*)p;   p += 256;
  float* h0    = (float*)p; p += (size_t)NN*128*4;
  float* h1    = (float*)p; p += (size_t)NN*128*4;   // ping-pong partner
  float* nodeout = (float*)p; p += (size_t)NN*16*4;
  int*   deg   = (int*)p;   p += (size_t)NN*4;
  int*   col   = (int*)p;   p += (size_t)NN*MAXDEG*4;
  float* wihT  = (float*)p; p += (size_t)3*49152*4;
  float* whhT  = (float*)p; p += (size_t)3*49152*4;
  float* WeffT = (float*)p; p += (size_t)9*49152*4;
  u16*   Bhi   = (u16*)p;   p += (size_t)9*512*256*2;
  u16*   Blo   = (u16*)p;   p += (size_t)9*512*256*2;
  u16*   B1hi  = (u16*)p;   p += 12288*2;
  u16*   B1lo  = (u16*)p;   p += 12288*2;
  u16*   B2hi  = (u16*)p;   p += 16384*2;
  u16*   B2lo  = (u16*)p;   p += 16384*2;

  k_detect<<<1, 512, 0, stream>>>(edge, batch, flags);
  hipMemsetAsync(deg, 0, (size_t)NN*4, stream);
  k_prep_wT<<<(147456 + 255)/256, 256, 0, stream>>>(gru_wih, gru_whh, wihT, whhT);
  k_weff<<<9*128, 384, 0, stream>>>(conv_w, wihT, WeffT);
  k_bsplit<<<9*512*256/256, 256, 0, stream>>>(WeffT, whhT, Bhi, Blo);
  k_bsplit_enc<<<(12288+16384)/256, 256, 0, stream>>>(node_w1, node_w2, B1hi, B1lo, B2hi, B2lo);
  k_fill_edges<<<NE/256, 256, 0, stream>>>(edge, flags, deg, col);
  k_enc_mfma<<<NN/32, 512, 0, stream>>>(x, pos, B1hi, B1lo, B2hi, B2lo,
      node_b1, node_b2, h0);

  float* hbuf[2] = { h0, h1 };
  for (int l = 0; l < 3; ++l){
    for (int i = 0; i < 3; ++i){
      int li = l*3 + i;
      k_fused<<<NN/32, 512, 0, stream>>>(deg, col, hbuf[li & 1], hbuf[(li + 1) & 1],
          Bhi + (size_t)li*131072, Blo + (size_t)li*131072,
          gru_bih + l*384, gru_bhh + l*384, (i==2) ? 1 : 0);
    }
  }
  k_head_n<<<NN/8, 64, 0, stream>>>(hbuf[1], lin1_w, lin1_b, lin2_w, lin2_b, nodeout);
  k_reduce<<<NG, 256, 0, stream>>>(nodeout, batch, flags, out);
}

// Round 13
// 1804.089 us; speedup vs baseline: 1.5888x; 1.0437x over previous
//
#include <hip/hip_runtime.h>

#define NN 100000
#define NE 1600000
#define NG 64
#define MAXDEG 64

typedef long long i64;
typedef unsigned short u16;
typedef unsigned int u32;
typedef __attribute__((ext_vector_type(8))) _Float16 f16x8;
typedef __attribute__((ext_vector_type(4))) _Float16 half4;
typedef __attribute__((ext_vector_type(4))) float f32x4;

__device__ __forceinline__ float sigm(float x){ return 1.f/(1.f+__expf(-x)); }
__device__ __forceinline__ float tanh_(float x){ return 2.f/(1.f+__expf(-2.f*x)) - 1.f; }
__device__ __forceinline__ f32x4 mfma16h(f16x8 a, f16x8 b, f32x4 c){
  return __builtin_amdgcn_mfma_f32_16x16x32_f16(a,b,c,0,0,0);
}
__device__ __forceinline__ u16 h2u(_Float16 h){ return *(const u16*)&h; }

// ---------------- int-width detection ----------------
__global__ __launch_bounds__(512) void k_detect(const int* __restrict__ ei,
    const int* __restrict__ batch, int* __restrict__ flags){
  int t = threadIdx.x;
  __shared__ int nz_e, nz_b;
  if (t == 0){ nz_e = 0; nz_b = 0; }
  __syncthreads();
  if (ei[2*t + 1] != 0) nz_e = 1;
  int k = NN/2 - 512 + t;
  if (batch[2*k + 1] != 0) nz_b = 1;
  __syncthreads();
  if (t == 0){ flags[0] = nz_e ? 0 : 1; flags[1] = nz_b ? 0 : 1; }
}

// ---------------- transposed GRU weights: wT[l][k][jc] = w[l][jc][k] ----------------
__global__ __launch_bounds__(256) void k_prep_wT(const float* __restrict__ wih,
    const float* __restrict__ whh, float* __restrict__ wihT, float* __restrict__ whhT){
  int idx = blockIdx.x*256 + threadIdx.x;            // 3*49152 = 147456
  if (idx >= 3*49152) return;
  int l = idx/49152, r = idx - l*49152, k = r/384, jc = r - k*384;
  wihT[idx] = wih[((size_t)l*384 + jc)*128 + k];
  whhT[idx] = whh[((size_t)l*384 + jc)*128 + k];
}

// ---------------- Weff fold: WeffT[li][k][jc] = sum_m cw[li][k][m] * wih[l][jc][m] ----------------
__global__ __launch_bounds__(384) void k_weff(const float* __restrict__ convw,
    const float* __restrict__ wihT, float* __restrict__ WeffT){
  int bid = blockIdx.x;               // 9*128
  int li = bid >> 7, k = bid & 127;
  int l = li / 3;
  int j = threadIdx.x;                // 0..383
  __shared__ float cwrow[128];
  if (j < 128) cwrow[j] = convw[((size_t)li*128 + k)*128 + j];
  __syncthreads();
  const float* wT = wihT + (size_t)l*49152;
  float acc = 0.f;
#pragma unroll 8
  for (int m = 0; m < 128; ++m)
    acc = fmaf(cwrow[m], wT[(size_t)m*384 + j], acc);
  WeffT[(size_t)li*49152 + (size_t)k*384 + j] = acc;
}

// ---------------- split fp16 B planes (GRU), MFMA-fragment-contiguous layout ----------------
__global__ __launch_bounds__(256) void k_bsplit(const float* __restrict__ WeffT,
    const float* __restrict__ whhT, u16* __restrict__ Bhi, u16* __restrict__ Blo){
  int idx = blockIdx.x*256 + threadIdx.x;   // 9*512*256 exact
  int li = idx >> 17;
  int r = idx & 131071;
  int col = r >> 8, k = r & 255;
  int l = li / 3;
  float v = 0.f;
  if (k < 128){
    if (col < 384) v = WeffT[(size_t)li*49152 + (size_t)k*384 + col];
  } else {
    int k2 = k - 128;
    if (col < 256)       v = whhT[(size_t)l*49152 + (size_t)k2*384 + col];
    else if (col >= 384) v = whhT[(size_t)l*49152 + (size_t)k2*384 + (col-128)];
  }
  _Float16 hi = (_Float16)v;
  _Float16 lo = (_Float16)(v - (float)hi);
  size_t widx = (size_t)li*131072 + ((((size_t)(k>>5))*512 + col)*4 + ((k>>3)&3))*8 + (k&7);
  Bhi[widx] = h2u(hi);
  Blo[widx] = h2u(lo);
}

// ---------------- split fp16 B planes (encoder W1 67->96pad, W2 128) ----------------
__global__ __launch_bounds__(256) void k_bsplit_enc(const float* __restrict__ w1,
    const float* __restrict__ w2, u16* __restrict__ B1hi, u16* __restrict__ B1lo,
    u16* __restrict__ B2hi, u16* __restrict__ B2lo){
  int idx = blockIdx.x*256 + threadIdx.x;    // 12288 + 16384 = 28672 exact
  if (idx < 12288){
    int j = idx / 96, k = idx - j*96;
    float v = (k < 67) ? w1[k*128 + j] : 0.f;
    _Float16 hi = (_Float16)v;
    _Float16 lo = (_Float16)(v - (float)hi);
    size_t widx = ((((size_t)(k>>5))*128 + j)*4 + ((k>>3)&3))*8 + (k&7);
    B1hi[widx] = h2u(hi);
    B1lo[widx] = h2u(lo);
  } else {
    int r = idx - 12288;
    int j = r >> 7, k = r & 127;
    float v = w2[k*128 + j];
    _Float16 hi = (_Float16)v;
    _Float16 lo = (_Float16)(v - (float)hi);
    size_t widx = ((((size_t)(k>>5))*128 + j)*4 + ((k>>3)&3))*8 + (k&7);
    B2hi[widx] = h2u(hi);
    B2lo[widx] = h2u(lo);
  }
}

// ---------------- padded adjacency by dst ----------------
__global__ __launch_bounds__(256) void k_fill_edges(const int* __restrict__ ei,
    const int* __restrict__ flags, int* __restrict__ deg, int* __restrict__ col){
  int e = blockIdx.x*256 + threadIdx.x;
  if (e >= NE) return;
  int s, d;
  if (flags[0]){
    const i64* e64 = (const i64*)ei;
    s = (int)e64[e]; d = (int)e64[NE + e];
  } else {
    s = ei[e]; d = ei[NE + e];
  }
  int slot = atomicAdd(&deg[d], 1);
  if (slot < MAXDEG) col[(size_t)d*MAXDEG + slot] = s;
}

// ---------------- encoder: split-fp16 MFMA, 32-row tile, 8 waves, robust zero-fill (proven r12) ----------------
__global__ __launch_bounds__(512, 8) void k_enc_mfma(const float* __restrict__ x,
    const float* __restrict__ pos,
    const u16* __restrict__ B1hi, const u16* __restrict__ B1lo,
    const u16* __restrict__ B2hi, const u16* __restrict__ B2lo,
    const float* __restrict__ b1, const float* __restrict__ b2, float* __restrict__ h){
  __shared__ u16 lds[4*32*128];                 // 32 KB
  u16* Ahi = lds;            u16* Alo = lds + 4096;
  u16* Thi = lds + 8192;     u16* Tlo = lds + 12288;
  const int tid = threadIdx.x, lane = tid & 63, w = tid >> 6;
  const int tile = blockIdx.x * 32;             // NN/32 exact

  // phase 0: zero-fill ENTIRE Ahi/Alo planes
  {
    int o = tid * 8;
    half4 z = {0,0,0,0};
    *(half4*)(Ahi + o) = z;  *(half4*)(Ahi + o + 4) = z;
    *(half4*)(Alo + o) = z;  *(half4*)(Alo + o + 4) = z;
  }
  __syncthreads();

  // phase 1: stage x (cols 0..63) + pos (cols 64..67 as one half4, 67=0)
  {
    int row = tid >> 4, colq = tid & 15;
    float4 v = *(const float4*)(x + (size_t)(tile+row)*64 + colq*4);
    int colu = colq*4;
    int cs = (colu >> 3) ^ (row & 7);
    int idx = row*128 + cs*8 + (colu & 7);
    _Float16 h0=(_Float16)v.x, h1=(_Float16)v.y, h2=(_Float16)v.z, h3=(_Float16)v.w;
    _Float16 l0=(_Float16)(v.x-(float)h0), l1=(_Float16)(v.y-(float)h1),
             l2=(_Float16)(v.z-(float)h2), l3=(_Float16)(v.w-(float)h3);
    half4 hv = {h0,h1,h2,h3};
    half4 lv = {l0,l1,l2,l3};
    *(half4*)(Ahi + idx) = hv;
    *(half4*)(Alo + idx) = lv;
  }
  if (tid < 32){
    int row = tid;
    int n = tile + row;
    float p0 = pos[(size_t)n*3], p1 = pos[(size_t)n*3+1], p2 = pos[(size_t)n*3+2];
    _Float16 h0=(_Float16)p0, h1=(_Float16)p1, h2=(_Float16)p2;
    _Float16 l0=(_Float16)(p0-(float)h0), l1=(_Float16)(p1-(float)h1), l2=(_Float16)(p2-(float)h2);
    int cs = 8 ^ (row & 7);                    // colu=64 -> chunk 8
    int idx = row*128 + cs*8;
    half4 hv = {h0,h1,h2,(_Float16)0.f};
    half4 lv = {l0,l1,l2,(_Float16)0.f};
    *(half4*)(Ahi + idx) = hv;
    *(half4*)(Alo + idx) = lv;
  }
  __syncthreads();

  const f32x4 fz = {0.f,0.f,0.f,0.f};
  // layer 1: K=96 (kk 0..2)
  f32x4 acc1[2] = {fz, fz};
#pragma unroll
  for (int kk = 0; kk < 3; ++kk){
    f16x8 a_hi[2], a_lo[2];
#pragma unroll
    for (int R=0;R<2;++R){
      int arow = R*16 + (lane&15);
      int cs = (kk*4 + (lane>>4)) ^ (arow & 7);
      a_hi[R] = *(const f16x8*)(Ahi + arow*128 + cs*8);
      a_lo[R] = *(const f16x8*)(Alo + arow*128 + cs*8);
    }
    int colg = w*16 + (lane&15);
    size_t boff = (((size_t)kk*128 + colg)*4 + (lane>>4))*8;
    f16x8 bh = *(const f16x8*)(B1hi + boff);
    f16x8 bl = *(const f16x8*)(B1lo + boff);
#pragma unroll
    for (int R=0;R<2;++R){
      acc1[R] = mfma16h(a_hi[R], bh, acc1[R]);
      acc1[R] = mfma16h(a_hi[R], bl, acc1[R]);
      acc1[R] = mfma16h(a_lo[R], bh, acc1[R]);
    }
  }
  // relu + bias -> T (split fp16, swizzled)
  {
    int jj = w*16 + (lane&15);
    float bias1 = b1[jj];
#pragma unroll
    for (int R=0;R<2;++R)
#pragma unroll
      for (int v=0;v<4;++v){
        int r_ = R*16 + ((lane>>4)<<2) + v;
        float t = fmaxf(acc1[R][v] + bias1, 0.f);
        _Float16 hi = (_Float16)t;
        _Float16 lo = (_Float16)(t - (float)hi);
        int cs = (jj >> 3) ^ (r_ & 7);
        int idx = r_*128 + cs*8 + (jj & 7);
        Thi[idx] = h2u(hi);
        Tlo[idx] = h2u(lo);
      }
  }
  __syncthreads();

  // layer 2: K=128 (kk 0..3)
  f32x4 acc2[2] = {fz, fz};
#pragma unroll
  for (int kk = 0; kk < 4; ++kk){
    f16x8 a_hi[2], a_lo[2];
#pragma unroll
    for (int R=0;R<2;++R){
      int arow = R*16 + (lane&15);
      int cs = (kk*4 + (lane>>4)) ^ (arow & 7);
      a_hi[R] = *(const f16x8*)(Thi + arow*128 + cs*8);
      a_lo[R] = *(const f16x8*)(Tlo + arow*128 + cs*8);
    }
    int colg = w*16 + (lane&15);
    size_t boff = (((size_t)kk*128 + colg)*4 + (lane>>4))*8;
    f16x8 bh = *(const f16x8*)(B2hi + boff);
    f16x8 bl = *(const f16x8*)(B2lo + boff);
#pragma unroll
    for (int R=0;R<2;++R){
      acc2[R] = mfma16h(a_hi[R], bh, acc2[R]);
      acc2[R] = mfma16h(a_hi[R], bl, acc2[R]);
      acc2[R] = mfma16h(a_lo[R], bh, acc2[R]);
    }
  }
  // bias -> fout -> coalesced store
  float* fout = (float*)lds;
  {
    int jj = w*16 + (lane&15);
    float bias2 = b2[jj];
#pragma unroll
    for (int R=0;R<2;++R)
#pragma unroll
      for (int v=0;v<4;++v){
        int r_ = R*16 + ((lane>>4)<<2) + v;
        fout[r_*128 + jj] = acc2[R][v] + bias2;
      }
  }
  __syncthreads();
#pragma unroll
  for (int i = 0; i < 2; ++i){
    int f = i*512 + tid;
    int row = f >> 5, colq = f & 31;
    float4 vv = *(const float4*)(fout + row*128 + colq*4);
    *(float4*)(h + (size_t)(tile+row)*128 + colq*4) = vv;
  }
}

// ---------------- FUSED v4 (proven r11): gather (4-deep MLP) + split-fp16 3-pass MFMA GRU ----------------
__global__ __launch_bounds__(512, 8) void k_fused(const int* __restrict__ deg,
    const int* __restrict__ col, const float* __restrict__ hin, float* __restrict__ hout,
    const u16* __restrict__ Bhi, const u16* __restrict__ Blo,
    const float* __restrict__ bih, const float* __restrict__ bhh, int apply_relu){
  __shared__ u16 Ahi[32*256];
  __shared__ u16 Alo[32*256];
  const int tid = threadIdx.x, lane = tid & 63, w = tid >> 6;   // w in 0..7
  const int tile = blockIdx.x * 32;                             // 3125*32 = NN exact

  // stage h-half (cols 128..255)
#pragma unroll
  for (int i = 0; i < 2; ++i){
    int f = i*512 + tid;
    int row = f >> 5, colq = f & 31;
    float4 v = *(const float4*)(hin + (size_t)(tile+row)*128 + colq*4);
    int colu = 128 + colq*4;
    int cs = (colu >> 3) ^ (row & 7);
    int idx = row*256 + cs*8 + (colu & 7);
    _Float16 h0=(_Float16)v.x, h1=(_Float16)v.y, h2=(_Float16)v.z, h3=(_Float16)v.w;
    _Float16 l0=(_Float16)(v.x-(float)h0), l1=(_Float16)(v.y-(float)h1),
             l2=(_Float16)(v.z-(float)h2), l3=(_Float16)(v.w-(float)h3);
    half4 hv = {h0,h1,h2,h3};
    half4 lv = {l0,l1,l2,l3};
    *(half4*)(Ahi + idx) = hv;
    *(half4*)(Alo + idx) = lv;
  }

  // gather ah-half (cols 0..127): 2 rows/wave; lane-half owns a row, 4-deep MLP
  const int half = lane >> 5, ln32 = lane & 31;
#pragma unroll
  for (int rr = 0; rr < 2; ++rr){
    int row = rr*16 + w*2 + half;
    int node = tile + row;
    int d = deg[node]; d = min(d, MAXDEG);
    int src1 = col[(size_t)node*MAXDEG + ln32];
    int src2 = col[(size_t)node*MAXDEG + 32 + ln32];
    float ax=0.f, ay=0.f, az=0.f, aw=0.f;
    int d1 = min(d, 32);
    int s = 0;
    for (; s + 3 < d1; s += 4){
      int a0 = __shfl(src1, half*32 + s, 64);
      int a1 = __shfl(src1, half*32 + s + 1, 64);
      int a2 = __shfl(src1, half*32 + s + 2, 64);
      int a3 = __shfl(src1, half*32 + s + 3, 64);
      float4 v0 = *(const float4*)(hin + (size_t)a0*128 + (ln32<<2));
      float4 v1 = *(const float4*)(hin + (size_t)a1*128 + (ln32<<2));
      float4 v2 = *(const float4*)(hin + (size_t)a2*128 + (ln32<<2));
      float4 v3 = *(const float4*)(hin + (size_t)a3*128 + (ln32<<2));
      ax += v0.x + v1.x + v2.x + v3.x;
      ay += v0.y + v1.y + v2.y + v3.y;
      az += v0.z + v1.z + v2.z + v3.z;
      aw += v0.w + v1.w + v2.w + v3.w;
    }
    for (; s < d1; ++s){
      int a0 = __shfl(src1, half*32 + s, 64);
      float4 v0 = *(const float4*)(hin + (size_t)a0*128 + (ln32<<2));
      ax += v0.x; ay += v0.y; az += v0.z; aw += v0.w;
    }
    int d2 = d - d1;
    s = 0;
    for (; s + 3 < d2; s += 4){
      int a0 = __shfl(src2, half*32 + s, 64);
      int a1 = __shfl(src2, half*32 + s + 1, 64);
      int a2 = __shfl(src2, half*32 + s + 2, 64);
      int a3 = __shfl(src2, half*32 + s + 3, 64);
      float4 v0 = *(const float4*)(hin + (size_t)a0*128 + (ln32<<2));
      float4 v1 = *(const float4*)(hin + (size_t)a1*128 + (ln32<<2));
      float4 v2 = *(const float4*)(hin + (size_t)a2*128 + (ln32<<2));
      float4 v3 = *(const float4*)(hin + (size_t)a3*128 + (ln32<<2));
      ax += v0.x + v1.x + v2.x + v3.x;
      ay += v0.y + v1.y + v2.y + v3.y;
      az += v0.z + v1.z + v2.z + v3.z;
      aw += v0.w + v1.w + v2.w + v3.w;
    }
    for (; s < d2; ++s){
      int a0 = __shfl(src2, half*32 + s, 64);
      float4 v0 = *(const float4*)(hin + (size_t)a0*128 + (ln32<<2));
      ax += v0.x; ay += v0.y; az += v0.z; aw += v0.w;
    }
    int colu = ln32 << 2;
    int cs = (colu >> 3) ^ (row & 7);
    int idx = row*256 + cs*8 + (colu & 7);
    _Float16 hx=(_Float16)ax, hy=(_Float16)ay, hz=(_Float16)az, hw=(_Float16)aw;
    _Float16 lx=(_Float16)(ax-(float)hx), ly=(_Float16)(ay-(float)hy),
             lz=(_Float16)(az-(float)hz), lw=(_Float16)(aw-(float)hw);
    half4 hv = {hx,hy,hz,hw};
    half4 lv = {lx,ly,lz,lw};
    *(half4*)(Ahi + idx) = hv;
    *(half4*)(Alo + idx) = lv;
  }
  __syncthreads();

  const f32x4 fz = {0.f,0.f,0.f,0.f};
  f32x4 acc[4][2];
#pragma unroll
  for (int g=0;g<4;++g)
#pragma unroll
    for (int R=0;R<2;++R) acc[g][R] = fz;

#pragma unroll
  for (int kk = 0; kk < 8; ++kk){
    f16x8 a_hi[2], a_lo[2];
#pragma unroll
    for (int R=0;R<2;++R){
      int arow = R*16 + (lane&15);
      int cs = (kk*4 + (lane>>4)) ^ (arow & 7);
      a_hi[R] = *(const f16x8*)(Ahi + arow*256 + cs*8);
      a_lo[R] = *(const f16x8*)(Alo + arow*256 + cs*8);
    }
#pragma unroll
    for (int g=0; g<4; ++g){
      if (g==2 && kk>=4) continue;   // inn: K[0,128) only
      if (g==3 && kk<4) continue;    // hn : K[128,256) only
      int colg = g*128 + w*16 + (lane&15);
      size_t boff = (((size_t)kk*512 + colg)*4 + (lane>>4))*8;
      f16x8 bh = *(const f16x8*)(Bhi + boff);
      f16x8 bl = *(const f16x8*)(Blo + boff);
#pragma unroll
      for (int R=0;R<2;++R){
        acc[g][R] = mfma16h(a_hi[R], bh, acc[g][R]);
        acc[g][R] = mfma16h(a_hi[R], bl, acc[g][R]);
        acc[g][R] = mfma16h(a_lo[R], bh, acc[g][R]);
      }
    }
  }

  // gate epilogue -> registers, then LDS-staged coalesced store
  float hn_reg[2][4];
  {
    int jj = w*16 + (lane&15);
    float br  = bih[jj]     + bhh[jj];
    float bz  = bih[128+jj] + bhh[128+jj];
    float bin = bih[256+jj];
    float bhn = bhh[256+jj];
#pragma unroll
    for (int R=0;R<2;++R)
#pragma unroll
      for (int v=0;v<4;++v){
        int r_ = R*16 + ((lane>>4)<<2) + v;
        float rg = sigm(acc[0][R][v] + br);
        float zg = sigm(acc[1][R][v] + bz);
        float hnv = acc[3][R][v] + bhn;
        float ng = tanh_(acc[2][R][v] + bin + rg*hnv);
        int colu = 128 + jj;
        int cs = (colu >> 3) ^ (r_ & 7);
        int lidx = r_*256 + cs*8 + (colu & 7);
        float hold = (float)(*(const _Float16*)(Ahi + lidx))
                   + (float)(*(const _Float16*)(Alo + lidx));
        float hnew = (1.f - zg)*ng + zg*hold;
        if (apply_relu) hnew = fmaxf(hnew, 0.f);
        hn_reg[R][v] = hnew;
      }
  }
  __syncthreads();
  float* fout = (float*)Ahi;               // reuse 16 KB as [32][128] f32
  {
    int jj = w*16 + (lane&15);
#pragma unroll
    for (int R=0;R<2;++R)
#pragma unroll
      for (int v=0;v<4;++v){
        int r_ = R*16 + ((lane>>4)<<2) + v;
        fout[r_*128 + jj] = hn_reg[R][v];
      }
  }
  __syncthreads();
#pragma unroll
  for (int i = 0; i < 2; ++i){
    int f = i*512 + tid;
    int row = f >> 5, colq = f & 31;
    float4 vv = *(const float4*)(fout + row*128 + colq*4);
    *(float4*)(hout + (size_t)(tile+row)*128 + colq*4) = vv;
  }
}

// ---------------- head: fp32, 8 nodes/block ----------------
__global__ __launch_bounds__(64) void k_head_n(const float* __restrict__ h,
    const float* __restrict__ l1, const float* __restrict__ b1,
    const float* __restrict__ l2, const float* __restrict__ b2, float* __restrict__ nodeout){
  int n0 = blockIdx.x * 8, j = threadIdx.x;
  __shared__ float hrow[8][128], t[8][64];
  for (int q = j; q < 1024; q += 64){
    int p = q >> 7, k = q & 127;
    hrow[p][k] = h[(size_t)(n0+p)*128 + k];
  }
  __syncthreads();
  float s[8];
#pragma unroll
  for (int p=0;p<8;++p) s[p] = b1[j];
  for (int k=0;k<128;++k){
    float w = l1[k*64 + j];
#pragma unroll
    for (int p=0;p<8;++p) s[p] = fmaf(hrow[p][k], w, s[p]);
  }
#pragma unroll
  for (int p=0;p<8;++p) t[p][j] = fmaxf(s[p], 0.f);
  __syncthreads();
  int c = j & 15;
#pragma unroll
  for (int pp=0;pp<2;++pp){
    int p = (j >> 4) + pp*4;
    float o = b2[c];
    for (int k=0;k<64;++k) o = fmaf(t[p][k], l2[k*16 + c], o);
    nodeout[(size_t)(n0+p)*16 + c] = o;
  }
}

// ---------------- per-graph readout: segmented reduce (batch is sorted) ----------------
__device__ __forceinline__ int lbound32(const int* __restrict__ a, int n, int v){
  int lo = 0, hi = n;
  while (lo < hi){ int mid = (lo+hi)>>1; if (a[mid] < v) lo = mid+1; else hi = mid; }
  return lo;
}
__device__ __forceinline__ int lbound64(const i64* __restrict__ a, int n, i64 v){
  int lo = 0, hi = n;
  while (lo < hi){ int mid = (lo+hi)>>1; if (a[mid] < v) lo = mid+1; else hi = mid; }
  return lo;
}
__global__ __launch_bounds__(256) void k_reduce(const float* __restrict__ nodeout,
    const int* __restrict__ batch, const int* __restrict__ flags, float* __restrict__ out){
  int g = blockIdx.x;
  int lo, hi;
  if (flags[1]){
    const i64* b64 = (const i64*)batch;
    lo = lbound64(b64, NN, (i64)g); hi = lbound64(b64, NN, (i64)g+1);
  } else {
    lo = lbound32(batch, NN, g); hi = lbound32(batch, NN, g+1);
  }
  int tid = threadIdx.x;
  int c = tid & 15, rr = tid >> 4;
  float s = 0.f;
  for (int r = lo + rr; r < hi; r += 16) s += nodeout[(size_t)r*16 + c];
  __shared__ float red[256];
  red[tid] = s; __syncthreads();
  for (int step = 128; step >= 16; step >>= 1){
    if (tid < step) red[tid] += red[tid + step];
    __syncthreads();
  }
  if (tid < 16) out[g*16 + tid] = red[tid];
}

// ---------------- launch ----------------
extern "C" void kernel_launch(void* const* d_in, const int* in_sizes, int n_in,
                              void* d_out, int out_size, void* d_ws, size_t ws_size,
                              hipStream_t stream){
  const float* x        = (const float*)d_in[0];
  const float* pos      = (const float*)d_in[1];
  const int*   edge     = (const int*)d_in[2];
  const int*   batch    = (const int*)d_in[3];
  const float* node_w1  = (const float*)d_in[4];
  const float* node_b1  = (const float*)d_in[5];
  const float* node_w2  = (const float*)d_in[6];
  const float* node_b2  = (const float*)d_in[7];
  const float* conv_w   = (const float*)d_in[8];
  const float* gru_wih  = (const float*)d_in[9];
  const float* gru_whh  = (const float*)d_in[10];
  const float* gru_bih  = (const float*)d_in[11];
  const float* gru_bhh  = (const float*)d_in[12];
  const float* lin1_w   = (const float*)d_in[13];
  const float* lin1_b   = (const float*)d_in[14];
  const float* lin2_w   = (const float*)d_in[15];
  const float* lin2_b   = (const float*)d_in[16];
  float* out = (float*)d_out;

  char* p = (char*)d_ws;
  int*   flags = (int*)p;   p += 256;
  float* h0    = (float*)p; p += (size_t)NN*128*4;
  float* h1    = (float*)p; p += (size_t)NN*128*4;   // ping-pong partner
  float* nodeout = (float*)p; p += (size_t)NN*16*4;
  int*   deg   = (int*)p;   p += (size_t)NN*4;
  int*   col   = (int*)p;   p += (size_t)NN*MAXDEG*4;
  float* wihT  = (float*)p; p += (size_t)3*49152*4;
  float* whhT  = (float*)p; p += (size_t)3*49152*4;
  float* WeffT = (float*)p; p += (size_t)9*49152*4;
  u16*   Bhi   = (u16*)p;   p += (size_t)9*512*256*2;
  u16*   Blo   = (u16*)p;   p += (size_t)9*512*256*2;
  u16*   B1hi  = (u16*)p;   p += 12288*2;
  u16*   B1lo  = (u16*)p;   p += 12288*2;
  u16*   B2hi  = (u16*)p;   p += 16384*2;
  u16*   B2lo  = (u16*)p;   p += 16384*2;

  k_detect<<<1, 512, 0, stream>>>(edge, batch, flags);
  hipMemsetAsync(deg, 0, (size_t)NN*4, stream);
  k_prep_wT<<<(147456 + 255)/256, 256, 0, stream>>>(gru_wih, gru_whh, wihT, whhT);
  k_weff<<<9*128, 384, 0, stream>>>(conv_w, wihT, WeffT);
  k_bsplit<<<9*512*256/256, 256, 0, stream>>>(WeffT, whhT, Bhi, Blo);
  k_bsplit_enc<<<(12288+16384)/256, 256, 0, stream>>>(node_w1, node_w2, B1hi, B1lo, B2hi, B2lo);
  k_fill_edges<<<NE/256, 256, 0, stream>>>(edge, flags, deg, col);
  k_enc_mfma<<<NN/32, 512, 0, stream>>>(x, pos, B1hi, B1lo, B2hi, B2lo,
      node_b1, node_b2, h0);

  float* hbuf[2] = { h0, h1 };
  for (int l = 0; l < 3; ++l){
    for (int i = 0; i < 3; ++i){
      int li = l*3 + i;
      k_fused<<<NN/32, 512, 0, stream>>>(deg, col, hbuf[li & 1], hbuf[(li + 1) & 1],
          Bhi + (size_t)li*131072, Blo + (size_t)li*131072,
          gru_bih + l*384, gru_bhh + l*384, (i==2) ? 1 : 0);
    }
  }
  k_head_n<<<NN/8, 64, 0, stream>>>(hbuf[1], lin1_w, lin1_b, lin2_w, lin2_b, nodeout);
  k_reduce<<<NG, 256, 0, stream>>>(nodeout, batch, flags, out);
}